// Round 7
// baseline (1169.015 us; speedup 1.0000x reference)
//
#include <hip/hip_runtime.h>
#include <math.h>

#define KTOP 2000
#define MAXOUT 500
#define CANDCAP 4096          // candidate capacity (global buffers)
#define NSEL 3600             // approx-score rank margin for selection
#define RCC 32                // candidates per rescore_conv block (N-split x2)
#define RC2 16                // candidates per rescore_fc block

typedef __attribute__((ext_vector_type(8))) short short8;
typedef __attribute__((ext_vector_type(4))) float f32x4;
typedef __attribute__((ext_vector_type(4))) double f64x4;

__device__ __forceinline__ unsigned short f2bf(float f) {
  unsigned int u = __float_as_uint(f);
  unsigned int r = ((u >> 16) & 1u) + 0x7FFFu;
  return (unsigned short)((u + r) >> 16);
}

__device__ __forceinline__ void ld_lds16(const void* g, void* l) {
  __builtin_amdgcn_global_load_lds((const unsigned int*)g, (unsigned int*)l,
                                   16, 0, 0);
}

// raw barrier that does NOT drain vmcnt, with compiler+scheduler fences
__device__ __forceinline__ void hard_barrier() {
  asm volatile("" ::: "memory");
  __builtin_amdgcn_sched_barrier(0);
  __builtin_amdgcn_s_barrier();
  __builtin_amdgcn_sched_barrier(0);
  asm volatile("" ::: "memory");
}

// ---------------------------------------------------------------------------
// transpose+convert: W[K][N] f32 -> WT[N][K] bf16.  grid (K/32, N/32), 256 thr
// ---------------------------------------------------------------------------
__global__ __launch_bounds__(256) void transpose_bf16_kernel(
    const float* __restrict__ W, unsigned short* __restrict__ WT, int K, int N)
{
  __shared__ float t[32][33];
  const int k0 = blockIdx.x << 5, n0 = blockIdx.y << 5;
  const int tid = threadIdx.x;
  const int r = tid >> 5, c = tid & 31;
#pragma unroll
  for (int p = 0; p < 4; ++p)
    t[r + (p << 3)][c] = W[(size_t)(k0 + r + (p << 3)) * N + n0 + c];
  __syncthreads();
#pragma unroll
  for (int p = 0; p < 4; ++p)
    WT[(size_t)(n0 + r + (p << 3)) * K + k0 + c] = f2bf(t[c][r + (p << 3)]);
}

// ---------------------------------------------------------------------------
// prep WiB: Wi[288][64] f32 -> WiB[tap(9)][co(64)][ci(32)] bf16
// ---------------------------------------------------------------------------
__global__ __launch_bounds__(256) void prep_wib_kernel(
    const float* __restrict__ Wi, unsigned short* __restrict__ WiB)
{
  const int t = blockIdx.x * 256 + threadIdx.x;
  if (t < 9 * 64 * 32) {
    const int tap = t / 2048, r = t & 2047, co = r >> 5, ci = r & 31;
    WiB[t] = f2bf(Wi[((size_t)tap * 32 + ci) * 64 + co]);
  }
}

// ---------------------------------------------------------------------------
// pad+convert df: [256][256][128] f32 -> [258][258][128] bf16 with zero halo.
// ---------------------------------------------------------------------------
__global__ __launch_bounds__(256) void pad_df_bf16(
    const float* __restrict__ df, unsigned short* __restrict__ dfb)
{
  const int t = blockIdx.x * 256 + threadIdx.x;
  if (t >= 258 * 258 * 16) return;
  const int p = t >> 4;              // padded pixel id
  const int c8 = (t & 15) << 3;      // channel base
  const int gy = p / 258 - 1, gx = p % 258 - 1;
  uint4 out = make_uint4(0, 0, 0, 0);
  if (gy >= 0 && gy < 256 && gx >= 0 && gx < 256) {
    const float* src = &df[((size_t)(gy * 256 + gx)) * 128 + c8];
    const float4 v0 = *(const float4*)src;
    const float4 v1 = *(const float4*)(src + 4);
    out.x = (unsigned int)f2bf(v0.x) | ((unsigned int)f2bf(v0.y) << 16);
    out.y = (unsigned int)f2bf(v0.z) | ((unsigned int)f2bf(v0.w) << 16);
    out.z = (unsigned int)f2bf(v1.x) | ((unsigned int)f2bf(v1.y) << 16);
    out.w = (unsigned int)f2bf(v1.z) | ((unsigned int)f2bf(v1.w) << 16);
  }
  *(uint4*)&dfb[(size_t)p * 128 + c8] = out;
}

// ---------------------------------------------------------------------------
// 8-phase 256x256x64 K-tile body: 4 quadrant phases, minimal ds_read reuse
// (A held across nh-phases, both B halves held), setprio around MFMA.
// ---------------------------------------------------------------------------
__device__ __forceinline__ void ktile_phases(
    const unsigned short* __restrict__ A0, const unsigned short* __restrict__ B0,
    const int arow, const int brow, const int ok0, const int ok1,
    f32x4 (&acc)[8][4])
{
  short8 Af[4][2], Bf[2][2][2];
  // ---- phase 0: read A(mh=0) + B(nh=0); MFMA Q(0,0)
#pragma unroll
  for (int m = 0; m < 4; ++m) {
    Af[m][0] = *(const short8*)&A0[((arow + (m << 4)) << 6) + ok0];
    Af[m][1] = *(const short8*)&A0[((arow + (m << 4)) << 6) + ok1];
  }
#pragma unroll
  for (int n = 0; n < 2; ++n) {
    Bf[0][n][0] = *(const short8*)&B0[((brow + (n << 4)) << 6) + ok0];
    Bf[0][n][1] = *(const short8*)&B0[((brow + (n << 4)) << 6) + ok1];
  }
  hard_barrier();
  __builtin_amdgcn_s_setprio(1);
#pragma unroll
  for (int m = 0; m < 4; ++m)
#pragma unroll
    for (int n = 0; n < 2; ++n) {
      acc[m][n] = __builtin_amdgcn_mfma_f32_16x16x32_bf16(Af[m][0], Bf[0][n][0], acc[m][n], 0, 0, 0);
      acc[m][n] = __builtin_amdgcn_mfma_f32_16x16x32_bf16(Af[m][1], Bf[0][n][1], acc[m][n], 0, 0, 0);
    }
  __builtin_amdgcn_s_setprio(0);
  hard_barrier();
  // ---- phase 1: read B(nh=1); MFMA Q(0,1)
#pragma unroll
  for (int n = 0; n < 2; ++n) {
    Bf[1][n][0] = *(const short8*)&B0[((brow + ((n + 2) << 4)) << 6) + ok0];
    Bf[1][n][1] = *(const short8*)&B0[((brow + ((n + 2) << 4)) << 6) + ok1];
  }
  hard_barrier();
  __builtin_amdgcn_s_setprio(1);
#pragma unroll
  for (int m = 0; m < 4; ++m)
#pragma unroll
    for (int n = 0; n < 2; ++n) {
      acc[m][n + 2] = __builtin_amdgcn_mfma_f32_16x16x32_bf16(Af[m][0], Bf[1][n][0], acc[m][n + 2], 0, 0, 0);
      acc[m][n + 2] = __builtin_amdgcn_mfma_f32_16x16x32_bf16(Af[m][1], Bf[1][n][1], acc[m][n + 2], 0, 0, 0);
    }
  __builtin_amdgcn_s_setprio(0);
  hard_barrier();
  // ---- phase 2: read A(mh=1); MFMA Q(1,1)
#pragma unroll
  for (int m = 0; m < 4; ++m) {
    Af[m][0] = *(const short8*)&A0[((arow + 64 + (m << 4)) << 6) + ok0];
    Af[m][1] = *(const short8*)&A0[((arow + 64 + (m << 4)) << 6) + ok1];
  }
  hard_barrier();
  __builtin_amdgcn_s_setprio(1);
#pragma unroll
  for (int m = 0; m < 4; ++m)
#pragma unroll
    for (int n = 0; n < 2; ++n) {
      acc[m + 4][n + 2] = __builtin_amdgcn_mfma_f32_16x16x32_bf16(Af[m][0], Bf[1][n][0], acc[m + 4][n + 2], 0, 0, 0);
      acc[m + 4][n + 2] = __builtin_amdgcn_mfma_f32_16x16x32_bf16(Af[m][1], Bf[1][n][1], acc[m + 4][n + 2], 0, 0, 0);
    }
  __builtin_amdgcn_s_setprio(0);
  hard_barrier();
  // ---- phase 3: no reads; MFMA Q(1,0) with held Bf[0]
  __builtin_amdgcn_s_setprio(1);
#pragma unroll
  for (int m = 0; m < 4; ++m)
#pragma unroll
    for (int n = 0; n < 2; ++n) {
      acc[m + 4][n] = __builtin_amdgcn_mfma_f32_16x16x32_bf16(Af[m][0], Bf[0][n][0], acc[m + 4][n], 0, 0, 0);
      acc[m + 4][n] = __builtin_amdgcn_mfma_f32_16x16x32_bf16(Af[m][1], Bf[0][n][1], acc[m + 4][n], 0, 0, 0);
    }
  __builtin_amdgcn_s_setprio(0);
  hard_barrier();
}

// ---------------------------------------------------------------------------
// conv1: 3x3 128->1024 + bias + relu -> x1b.  256x256 tile, BK=64, 8 waves,
// 8-phase schedule, counted vmcnt(8) double-buffered global_load_lds.
// ---------------------------------------------------------------------------
__global__ __launch_bounds__(512) void conv1_mfma(
    const unsigned short* __restrict__ dfb, const unsigned short* __restrict__ WcT,
    const float* __restrict__ bc, unsigned short* __restrict__ x1b, int pt0)
{
  __shared__ __align__(16) unsigned short smem[65536];   // 128 KB
  const int tid = threadIdx.x;
  const int wv = tid >> 6, lane = tid & 63;
  const int wr = wv >> 2, wc = wv & 3;
  const int l15 = lane & 15, quad = lane >> 4;
  const int n0 = blockIdx.x << 8;
  const int lm0 = blockIdx.y << 8;
  const int Pbase = (pt0 << 6) + lm0;   // multiple of 256
  const int y = Pbase >> 8;
  const int tr = tid >> 3, g8 = tid & 7;
  const int xg = ((g8 ^ (tr & 7)) << 4);           // swizzled source byte off
  const int axr = l15 & 7;
  const int ok0 = ((quad ^ axr) << 3);
  const int ok1 = (((4 + quad) ^ axr) << 3);
  const int arow = (wr << 7) + l15;
  const int brow = (wc << 6) + l15;

  // preload bias BEFORE any global_load_lds (keeps vmcnt counting exact)
  float bcv[4];
#pragma unroll
  for (int j = 0; j < 4; ++j) bcv[j] = bc[n0 + (wc << 6) + (j << 4) + l15];

  f32x4 acc[8][4];
  const f32x4 z4 = {0.f, 0.f, 0.f, 0.f};
#pragma unroll
  for (int i = 0; i < 8; ++i)
#pragma unroll
    for (int j = 0; j < 4; ++j) acc[i][j] = z4;

  const char* WB = (const char*)WcT + ((size_t)(n0 + tr) * 1152) * 2 + xg;
  unsigned short* lA = &smem[(tr << 6) + (g8 << 3)];

  auto issue = [&](int kt, int buf) {
    const int tap = kt >> 1, ci0 = (kt & 1) << 6;
    const int dy = tap / 3 - 1, dx = tap % 3 - 1;
    const char* Ab = (const char*)dfb +
        (((size_t)((y + dy + 1) * 258 + dx + 1)) * 128 + ci0) * 2 +
        (size_t)tr * 256 + xg;
    unsigned short* la = lA + buf * 32768;
    unsigned short* lb = la + 16384;
    const char* Bb = WB + (size_t)kt * 128;
#pragma unroll
    for (int i = 0; i < 4; ++i)
      ld_lds16(Ab + (size_t)i * 16384, la + i * 4096);
#pragma unroll
    for (int i = 0; i < 4; ++i)
      ld_lds16(Bb + (size_t)i * 147456, lb + i * 4096);
  };

  issue(0, 0);
  issue(1, 1);
#pragma unroll 2
  for (int kt = 0; kt < 18; ++kt) {
    const int buf = kt & 1;
    if (kt < 17) asm volatile("s_waitcnt vmcnt(8)" ::: "memory");
    else         asm volatile("s_waitcnt vmcnt(0)" ::: "memory");
    hard_barrier();
    ktile_phases(&smem[buf * 32768], &smem[buf * 32768 + 16384],
                 arow, brow, ok0, ok1, acc);
    if (kt < 16) issue(kt + 2, buf);
  }

#pragma unroll
  for (int m = 0; m < 8; ++m)
#pragma unroll
    for (int n = 0; n < 4; ++n) {
      const int col = n0 + (wc << 6) + (n << 4) + l15;
      const float bb = bcv[n];
#pragma unroll
      for (int rg = 0; rg < 4; ++rg) {
        const int row = lm0 + (wr << 7) + (m << 4) + (quad << 2) + rg;
        const float v = fmaxf(acc[m][n][rg] + bb, 0.f);
        x1b[(size_t)row * 1024 + col] = f2bf(v);
      }
    }
}

// ---------------------------------------------------------------------------
// fc: 1x1 1024->1024 + bias + relu, fused score partials.  Same 8-phase
// structure; partial written per N-block (4 chunks).
// ---------------------------------------------------------------------------
__global__ __launch_bounds__(512) void fc_mfma(
    const unsigned short* __restrict__ x1b, const unsigned short* __restrict__ WfcT,
    const float* __restrict__ bfc, const float* __restrict__ Wsc,
    float* __restrict__ part, int pt0)
{
  __shared__ __align__(16) unsigned short smem[65536];   // 128 KB
  const int tid = threadIdx.x;
  const int wv = tid >> 6, lane = tid & 63;
  const int wr = wv >> 2, wc = wv & 3;
  const int l15 = lane & 15, quad = lane >> 4;
  const int n0 = blockIdx.x << 8;
  const int lm0 = blockIdx.y << 8;
  const int Pbase = (pt0 << 6) + lm0;
  const int tr = tid >> 3, g8 = tid & 7;
  const int xg = ((g8 ^ (tr & 7)) << 4);
  const int axr = l15 & 7;
  const int ok0 = ((quad ^ axr) << 3);
  const int ok1 = (((4 + quad) ^ axr) << 3);
  const int arow = (wr << 7) + l15;
  const int brow = (wc << 6) + l15;

  float wsv[4], bfv[4];
#pragma unroll
  for (int j = 0; j < 4; ++j) {
    const int col = n0 + (wc << 6) + (j << 4) + l15;
    wsv[j] = Wsc[col];
    bfv[j] = bfc[col];
  }

  f32x4 acc[8][4];
  const f32x4 z4 = {0.f, 0.f, 0.f, 0.f};
#pragma unroll
  for (int i = 0; i < 8; ++i)
#pragma unroll
    for (int j = 0; j < 4; ++j) acc[i][j] = z4;

  const char* AB = (const char*)x1b + ((size_t)(lm0 + tr) * 1024) * 2 + xg;
  const char* WB = (const char*)WfcT + ((size_t)(n0 + tr) * 1024) * 2 + xg;
  unsigned short* lA = &smem[(tr << 6) + (g8 << 3)];

  auto issue = [&](int kt, int buf) {
    unsigned short* la = lA + buf * 32768;
    unsigned short* lb = la + 16384;
    const char* Ab = AB + (size_t)kt * 128;
    const char* Bb = WB + (size_t)kt * 128;
#pragma unroll
    for (int i = 0; i < 4; ++i)
      ld_lds16(Ab + (size_t)i * 131072, la + i * 4096);
#pragma unroll
    for (int i = 0; i < 4; ++i)
      ld_lds16(Bb + (size_t)i * 131072, lb + i * 4096);
  };

  issue(0, 0);
  issue(1, 1);
#pragma unroll 2
  for (int kt = 0; kt < 16; ++kt) {
    const int buf = kt & 1;
    if (kt < 15) asm volatile("s_waitcnt vmcnt(8)" ::: "memory");
    else         asm volatile("s_waitcnt vmcnt(0)" ::: "memory");
    hard_barrier();
    ktile_phases(&smem[buf * 32768], &smem[buf * 32768 + 16384],
                 arow, brow, ok0, ok1, acc);
    if (kt < 14) issue(kt + 2, buf);
  }

  // fused score partial: per row, sum over this block's 256 cols
  float* red = (float*)smem;    // 256*5 floats
#pragma unroll
  for (int m = 0; m < 8; ++m)
#pragma unroll
    for (int rg = 0; rg < 4; ++rg) {
      float ps = 0.f;
#pragma unroll
      for (int n = 0; n < 4; ++n) {
        const float v = fmaxf(acc[m][n][rg] + bfv[n], 0.f);
        ps = fmaf(v, wsv[n], ps);
      }
      // butterfly over the 16 l15 lanes (stays within quad group)
#pragma unroll
      for (int off = 1; off <= 8; off <<= 1)
        ps += __shfl_xor(ps, off, 64);
      if (l15 == 0) {
        const int row = (wr << 7) + (m << 4) + (quad << 2) + rg;
        red[row * 5 + wc] = ps;
      }
    }
  __syncthreads();
  if (tid < 256) {
    float s = 0.f;
#pragma unroll
    for (int w8 = 0; w8 < 4; ++w8) s += red[tid * 5 + w8];
    part[(size_t)blockIdx.x * 65536 + Pbase + tid] = s;
  }
}

// ---------------------------------------------------------------------------
// finalize: sum 4 partials, bias, sigmoid -> f32 approx scores (selection)
// ---------------------------------------------------------------------------
__global__ __launch_bounds__(256) void head_finalize_kernel(
    const float* __restrict__ part, const float* __restrict__ bs,
    float* __restrict__ scores)
{
  const int pix = blockIdx.x * 256 + threadIdx.x;
  float s = 0.f;
#pragma unroll
  for (int cb = 0; cb < 4; ++cb) s += part[(size_t)cb * 65536 + pix];
  s += bs[0];
  scores[pix] = 1.f / (1.f + expf(-s));
}

// ---------------------------------------------------------------------------
// select: radix-select NSEL-th approx score (parallel suffix-scan bucket
// pick), then DETERMINISTIC prefix-scan compaction in ascending cell order.
// ---------------------------------------------------------------------------
__global__ __launch_bounds__(1024) void select_kernel(
    const float* __restrict__ scores, unsigned int* __restrict__ cand_idx,
    unsigned int* __restrict__ cand_cnt)
{
  __shared__ unsigned int hist[256];
  __shared__ unsigned int sh_prefix, sh_sub;
  __shared__ int scan_s[1024];
  const int tid = threadIdx.x;

  unsigned int prefix = 0u;
  int need = NSEL;
  for (int byte = 3; byte >= 0; --byte) {
    if (tid < 256) hist[tid] = 0u;
    __syncthreads();
    const int sh = byte * 8;
    const unsigned int mhi = (byte == 3) ? 0u : (0xFFFFFFFFu << (sh + 8));
    for (int i = tid; i < 65536; i += 1024) {
      const unsigned int b = __float_as_uint(scores[i]);
      if ((b & mhi) == prefix) atomicAdd(&hist[(b >> sh) & 255u], 1u);
    }
    __syncthreads();
    // in-place parallel suffix sum: hist[v] := sum_{v'>=v} hist[v']
    for (int off = 1; off < 256; off <<= 1) {
      unsigned int add = 0u;
      if (tid < 256 && tid + off < 256) add = hist[tid + off];
      __syncthreads();
      if (tid < 256) hist[tid] += add;
      __syncthreads();
    }
    if (tid < 256) {
      const unsigned int sv = hist[tid];
      const unsigned int above = (tid == 255) ? 0u : hist[tid + 1];
      if ((int)above < need && (int)sv >= need) {
        sh_prefix = prefix | ((unsigned)tid << sh);
        sh_sub = above;
      }
    }
    __syncthreads();
    prefix = sh_prefix;
    need -= (int)sh_sub;
    __syncthreads();
  }
  const float thr = __uint_as_float(prefix);

  // deterministic compaction: thread t owns cells [t*64, t*64+64)
  const int b0 = tid << 6;
  int my = 0;
  for (int k = 0; k < 64; ++k)
    if (scores[b0 + k] >= thr) ++my;
  scan_s[tid] = my;
  __syncthreads();
  for (int off = 1; off < 1024; off <<= 1) {
    const int a = scan_s[tid];
    const int b = (tid >= off) ? scan_s[tid - off] : 0;
    __syncthreads();
    scan_s[tid] = a + b;
    __syncthreads();
  }
  int pos = scan_s[tid] - my;     // exclusive prefix
  const int total = scan_s[1023];
  for (int k = 0; k < 64; ++k) {
    if (scores[b0 + k] >= thr) {
      if (pos < CANDCAP) cand_idx[pos] = (unsigned int)(b0 + k);
      ++pos;
    }
  }
  if (tid == 0)
    *cand_cnt = (unsigned int)(total > CANDCAP ? CANDCAP : total);
}

// ---------------------------------------------------------------------------
// rescore_conv via f64 MFMA: M=32 cand x N=512 co per block (N-split x2),
// K=1152.  512 thr, 8 waves.  Double-buffered patt with async-stage split
// (loads issued before MFMA section, LDS writes after) + depth-2 weight
// prefetch.  Accumulation order identical to previous version (bit-exact).
// ---------------------------------------------------------------------------
#define PSTR 133   // f64 LDS row stride (conflict-free for quad-strided b64)
__global__ __launch_bounds__(512) void rescore_conv(
    const float* __restrict__ df, const float* __restrict__ Wc,
    const float* __restrict__ bc,
    const unsigned int* __restrict__ cand_idx,
    const unsigned int* __restrict__ cand_cnt,
    double* __restrict__ x1g)
{
  __shared__ double patt[2][RCC * PSTR];   // 68 KB
  __shared__ int rrs[RCC], ccs[RCC];
  const int cnt = (int)*cand_cnt;
  const int nb = blockIdx.x & 1;
  const int c0 = (blockIdx.x >> 1) * RCC;
  if (c0 >= cnt) return;
  const int tid = threadIdx.x;
  const int wv = tid >> 6, lane = tid & 63;
  const int m = lane & 15, quad = lane >> 4;
  const int co_base = (nb << 9) + (wv << 6);

  if (tid < RCC) {
    const int slot = (c0 + tid < cnt) ? c0 + tid : c0;
    const unsigned int idx = cand_idx[slot];
    rrs[tid] = (int)(idx >> 8); ccs[tid] = (int)(idx & 255u);
  }
  __syncthreads();

  // per-thread staged elements: p = tid + j*512, j=0..7 (RCC*128/512 = 8)
  float sv[8];
  auto ldregs = [&](int tap) {
    const int dy = tap / 3 - 1, dx = tap % 3 - 1;
#pragma unroll
    for (int j = 0; j < 8; ++j) {
      const int p = tid + (j << 9);
      const int c = p >> 7, ci = p & 127;
      const int gy = rrs[c] + dy, gx = ccs[c] + dx;
      float v = 0.f;
      if (gy >= 0 && gy < 256 && gx >= 0 && gx < 256)
        v = df[((size_t)((gy << 8) + gx)) * 128 + ci];
      sv[j] = v;
    }
  };
  auto wrlds = [&](int b) {
#pragma unroll
    for (int j = 0; j < 8; ++j) {
      const int p = tid + (j << 9);
      const int c = p >> 7, ci = p & 127;
      patt[b][c * PSTR + ci] = (double)sv[j];
    }
  };

  f64x4 acc[2][4];
  const f64x4 z4 = {0.0, 0.0, 0.0, 0.0};
#pragma unroll
  for (int ct = 0; ct < 2; ++ct)
#pragma unroll
    for (int t = 0; t < 4; ++t) acc[ct][t] = z4;

  ldregs(0);
  wrlds(0);
  __syncthreads();
  int buf = 0;
  for (int tap = 0; tap < 9; ++tap) {
    if (tap < 8) ldregs(tap + 1);        // async: loads in flight over MFMA
    const float* wrow = &Wc[(size_t)(tap * 128 + quad) * 1024 + co_base + m];
    float wf[4], wn[4];
#pragma unroll
    for (int t = 0; t < 4; ++t) wf[t] = wrow[t << 4];
#pragma unroll
    for (int t = 0; t < 4; ++t) wn[t] = wrow[(size_t)4096 + (t << 4)];
    for (int k4 = 0; k4 < 32; ++k4) {
      float w2[4];
      if (k4 + 2 < 32) {
#pragma unroll
        for (int t = 0; t < 4; ++t)
          w2[t] = wrow[(size_t)((k4 + 2) << 2) * 1024 + (t << 4)];
      }
      const double a0 = patt[buf][m * PSTR + (k4 << 2) + quad];
      const double a1 = patt[buf][(16 + m) * PSTR + (k4 << 2) + quad];
#pragma unroll
      for (int t = 0; t < 4; ++t)
        acc[0][t] = __builtin_amdgcn_mfma_f64_16x16x4f64(a0, (double)wf[t], acc[0][t], 0, 0, 0);
#pragma unroll
      for (int t = 0; t < 4; ++t)
        acc[1][t] = __builtin_amdgcn_mfma_f64_16x16x4f64(a1, (double)wf[t], acc[1][t], 0, 0, 0);
      if (k4 + 1 < 32) {
#pragma unroll
        for (int t = 0; t < 4; ++t) wf[t] = wn[t];
      }
      if (k4 + 2 < 32) {
#pragma unroll
        for (int t = 0; t < 4; ++t) wn[t] = w2[t];
      }
    }
    if (tap < 8) wrlds(buf ^ 1);         // write-late; reads of buf^1 done
    __syncthreads();
    buf ^= 1;
  }
#pragma unroll
  for (int ct = 0; ct < 2; ++ct)
#pragma unroll
    for (int t = 0; t < 4; ++t) {
      const int co = co_base + (t << 4) + m;
      const double bb = (double)bc[co];
#pragma unroll
      for (int rg = 0; rg < 4; ++rg) {
        const int cand = (ct << 4) + (quad << 2) + rg;
        if (c0 + cand < cnt) {
          const double v = acc[ct][t][rg] + bb;
          x1g[(size_t)(c0 + cand) * 1024 + co] = v > 0.0 ? v : 0.0;
        }
      }
    }
}

// ---------------------------------------------------------------------------
// rescore_fc via f64 MFMA: M=16 cand, N=1024, K=1024; heads fused with
// deterministic butterfly + fixed-order wave combine.  512 thr.
// Double-buffered xbuf with async-stage split + depth-2 weight prefetch.
// ---------------------------------------------------------------------------
__global__ __launch_bounds__(512) void rescore_fc(
    const double* __restrict__ x1g, const float* __restrict__ Wfc,
    const float* __restrict__ bfc, const float* __restrict__ Wsc,
    const float* __restrict__ bs, const float* __restrict__ Wrg,
    const float* __restrict__ br,
    const unsigned int* __restrict__ cand_cnt,
    unsigned long long* __restrict__ cand_sb,
    double* __restrict__ cand_ry, double* __restrict__ cand_rx)
{
  __shared__ double xbuf[2][16 * PSTR];   // 34 KB
  __shared__ double partw[3][8][16];      // [head][wave][cand], 3 KB
  const int cnt = (int)*cand_cnt;
  const int c0 = blockIdx.x * RC2;
  if (c0 >= cnt) return;
  const int tid = threadIdx.x;
  const int wv = tid >> 6, lane = tid & 63;
  const int m = lane & 15, quad = lane >> 4;
  const int co_base = wv << 7;

  // per-thread staged elements: p = tid + j*512, j=0..3 (16*128/512 = 4)
  double sx[4];
  auto ldregs = [&](int kc) {
#pragma unroll
    for (int j = 0; j < 4; ++j) {
      const int p = tid + (j << 9);
      const int c = p >> 7, k = p & 127;
      const int row = (c0 + c < cnt) ? c0 + c : c0;
      sx[j] = x1g[(size_t)row * 1024 + (kc << 7) + k];
    }
  };
  auto wrlds = [&](int b) {
#pragma unroll
    for (int j = 0; j < 4; ++j) {
      const int p = tid + (j << 9);
      const int c = p >> 7, k = p & 127;
      xbuf[b][c * PSTR + k] = sx[j];
    }
  };

  f64x4 acc[8];
  const f64x4 z4 = {0.0, 0.0, 0.0, 0.0};
#pragma unroll
  for (int t = 0; t < 8; ++t) acc[t] = z4;

  ldregs(0);
  wrlds(0);
  __syncthreads();
  int buf = 0;
  for (int kc = 0; kc < 8; ++kc) {
    if (kc < 7) ldregs(kc + 1);          // async: loads in flight over MFMA
    const float* wrow = &Wfc[(size_t)((kc << 7) + quad) * 1024 + co_base + m];
    float wf[8], wn[8];
#pragma unroll
    for (int t = 0; t < 8; ++t) wf[t] = wrow[t << 4];
#pragma unroll
    for (int t = 0; t < 8; ++t) wn[t] = wrow[(size_t)4096 + (t << 4)];
    for (int k4 = 0; k4 < 32; ++k4) {
      float w2[8];
      if (k4 + 2 < 32) {
#pragma unroll
        for (int t = 0; t < 8; ++t)
          w2[t] = wrow[(size_t)((k4 + 2) << 2) * 1024 + (t << 4)];
      }
      const double a = xbuf[buf][m * PSTR + (k4 << 2) + quad];
#pragma unroll
      for (int t = 0; t < 8; ++t)
        acc[t] = __builtin_amdgcn_mfma_f64_16x16x4f64(a, (double)wf[t], acc[t], 0, 0, 0);
      if (k4 + 1 < 32) {
#pragma unroll
        for (int t = 0; t < 8; ++t) wf[t] = wn[t];
      }
      if (k4 + 2 < 32) {
#pragma unroll
        for (int t = 0; t < 8; ++t) wn[t] = w2[t];
      }
    }
    if (kc < 7) wrlds(buf ^ 1);
    __syncthreads();
    buf ^= 1;
  }

  // heads: per lane, 4 cands (reg) x 8 co (t)
  double ps[4] = {0, 0, 0, 0}, py[4] = {0, 0, 0, 0}, px[4] = {0, 0, 0, 0};
#pragma unroll
  for (int t = 0; t < 8; ++t) {
    const int co = co_base + (t << 4) + m;
    const double bfv = (double)bfc[co];
    const double wsv = (double)Wsc[co];
    const double w0 = (double)Wrg[co * 2], w1 = (double)Wrg[co * 2 + 1];
#pragma unroll
    for (int rg = 0; rg < 4; ++rg) {
      double v = acc[t][rg] + bfv;
      v = v > 0.0 ? v : 0.0;
      ps[rg] = fma(v, wsv, ps[rg]);
      py[rg] = fma(v, w0, py[rg]);
      px[rg] = fma(v, w1, px[rg]);
    }
  }
  // butterfly over the 16 m-lanes (xor 1,2,4,8) — deterministic fixed order
#pragma unroll
  for (int off = 1; off <= 8; off <<= 1) {
#pragma unroll
    for (int rg = 0; rg < 4; ++rg) {
      ps[rg] += __shfl_xor(ps[rg], off, 64);
      py[rg] += __shfl_xor(py[rg], off, 64);
      px[rg] += __shfl_xor(px[rg], off, 64);
    }
  }
  if (m == 0) {
#pragma unroll
    for (int rg = 0; rg < 4; ++rg) {
      const int cand = (quad << 2) + rg;
      partw[0][wv][cand] = ps[rg];
      partw[1][wv][cand] = py[rg];
      partw[2][wv][cand] = px[rg];
    }
  }
  __syncthreads();
  if (tid < 48) {
    const int cand = tid & 15, h = tid >> 4;
    double s = 0.0;
#pragma unroll
    for (int w8 = 0; w8 < 8; ++w8) s += partw[h][w8][cand];
    if (c0 + cand < cnt) {
      if (h == 0) {
        const double lg = s + (double)bs[0];
        const double sg = 1.0 / (1.0 + exp(-lg));
        cand_sb[c0 + cand] = (unsigned long long)__double_as_longlong(sg);
      } else if (h == 1) cand_ry[c0 + cand] = s + (double)br[0];
      else               cand_rx[c0 + cand] = s + (double)br[1];
    }
  }
}

// ---------------------------------------------------------------------------
// proposal: f64 radix-select top-2000 (parallel suffix-scan bucket pick),
// DETERMINISTIC compaction, bitonic sort with (score desc, slot asc)
// tie-break, f64 NMS with LDS-resident neighbor lists, emit.
// Dynamic LDS layout (102400 B):
//   sk   ull [2048]      @ 0       16384
//   si   uint[2048]      @ 16384    8192
//   scan int [2048]      @ 24576    8192
//   nbrs u16 [2048*16]   @ 32768   65536
//   kept u8  [2048]      @ 98304    2048
//   nbrc u8  [2048]      @ 100352   2048
// ---------------------------------------------------------------------------
#define PROP_LDS 102400
__global__ __launch_bounds__(1024) void proposal_kernel(
    const unsigned int* __restrict__ cand_idx,
    const unsigned int* __restrict__ cand_cnt,
    const unsigned long long* __restrict__ cand_sb,
    const double* __restrict__ cand_ry, const double* __restrict__ cand_rx,
    unsigned int* __restrict__ cellrank,
    double* __restrict__ cyg, double* __restrict__ cxg,
    int* __restrict__ startb, float* __restrict__ out_ps,
    float* __restrict__ out_dec)
{
  extern __shared__ __align__(16) char dynsm[];
  unsigned long long* sk = (unsigned long long*)dynsm;
  unsigned int* si = (unsigned int*)(dynsm + 16384);
  int* scan = (int*)(dynsm + 24576);
  unsigned short* nbrs = (unsigned short*)(dynsm + 32768);
  unsigned char* kept = (unsigned char*)(dynsm + 98304);
  unsigned char* nbrc = (unsigned char*)(dynsm + 100352);

  __shared__ unsigned int hist[256];
  __shared__ unsigned long long sh_pref;
  __shared__ unsigned int sh_sub;
  __shared__ volatile unsigned int changed;
  __shared__ int sh_maxreg;

  const int tid = threadIdx.x;
  const int cnt = (int)*cand_cnt;

  for (int i = tid; i < 65536; i += 1024) cellrank[i] = 0xFFFFFFFFu;

  // ---- radix-select the 2000th-largest f64-score bit pattern
  unsigned long long prefix = 0ull;
  int need = KTOP;
  for (int byte = 7; byte >= 0; --byte) {
    if (tid < 256) hist[tid] = 0u;
    __syncthreads();
    const int sh = byte * 8;
    const unsigned long long mhi =
        (byte == 7) ? 0ull : (0xFFFFFFFFFFFFFFFFull << (sh + 8));
    for (int i = tid; i < cnt; i += 1024) {
      const unsigned long long k = cand_sb[i];
      if ((k & mhi) == prefix) atomicAdd(&hist[(unsigned int)((k >> sh) & 255u)], 1u);
    }
    __syncthreads();
    // in-place parallel suffix sum over buckets
    for (int off = 1; off < 256; off <<= 1) {
      unsigned int add = 0u;
      if (tid < 256 && tid + off < 256) add = hist[tid + off];
      __syncthreads();
      if (tid < 256) hist[tid] += add;
      __syncthreads();
    }
    if (tid < 256) {
      const unsigned int sv = hist[tid];
      const unsigned int above = (tid == 255) ? 0u : hist[tid + 1];
      if ((int)above < need && (int)sv >= need) {
        sh_pref = prefix | ((unsigned long long)(unsigned)tid << sh);
        sh_sub = above;
      }
    }
    __syncthreads();
    prefix = sh_pref;
    need -= (int)sh_sub;
    __syncthreads();
  }
  const unsigned long long T = prefix;

  // ---- deterministic compaction: thread t owns slots [4t, 4t+4)
  const int s0 = tid << 2;
  unsigned long long kv[4];
  int ca = 0, cb = 0;
#pragma unroll
  for (int q = 0; q < 4; ++q) {
    const int s = s0 + q;
    kv[q] = (s < cnt) ? cand_sb[s] : 0ull;
    if (s < cnt) { if (kv[q] > T) ++ca; else if (kv[q] == T) ++cb; }
  }
  scan[tid] = ca;
  __syncthreads();
  for (int off = 1; off < 1024; off <<= 1) {
    const int a = scan[tid];
    const int b = (tid >= off) ? scan[tid - off] : 0;
    __syncthreads();
    scan[tid] = a + b;
    __syncthreads();
  }
  int posA = scan[tid] - ca;         // exclusive
  const int atot = scan[1023];
  __syncthreads();
  scan[tid] = cb;
  __syncthreads();
  for (int off = 1; off < 1024; off <<= 1) {
    const int a = scan[tid];
    const int b = (tid >= off) ? scan[tid - off] : 0;
    __syncthreads();
    scan[tid] = a + b;
    __syncthreads();
  }
  int posB = atot + (scan[tid] - cb);
  __syncthreads();
#pragma unroll
  for (int q = 0; q < 4; ++q) {
    const int s = s0 + q;
    if (s < cnt) {
      if (kv[q] > T) {
        sk[posA] = kv[q]; si[posA] = (unsigned int)s; ++posA;
      } else if (kv[q] == T) {
        if (posB < KTOP) { sk[posB] = kv[q]; si[posB] = (unsigned int)s; }
        ++posB;
      }
    }
  }
  __syncthreads();
  for (int i = tid; i < 2048; i += 1024)
    if (i >= KTOP) { sk[i] = 0ull; si[i] = 0u; }
  if (tid == 0) sh_maxreg = 0;
  __syncthreads();

  // ---- bitonic sort 2048 descending by (score bits, then ascending slot)
  for (int k = 2; k <= 2048; k <<= 1) {
    for (int j = k >> 1; j > 0; j >>= 1) {
      const int i = (tid & (j - 1)) | ((tid & ~(j - 1)) << 1);
      const int ixj = i | j;
      const unsigned long long a = sk[i], b = sk[ixj];
      const unsigned int ia = si[i], ib = si[ixj];
      const bool up = ((i & k) == 0);
      const bool lt = (a < b) || (a == b && ia > ib);
      const bool gt = (a > b) || (a == b && ia < ib);
      if (up ? lt : gt) {
        sk[i] = b; sk[ixj] = a;
        si[i] = ib; si[ixj] = ia;
      }
      __syncthreads();
    }
  }

  // ---- decode top-2000 (f64)
  for (int r = tid; r < KTOP; r += 1024) {
    const unsigned int slot = si[r];
    const unsigned int idx = cand_idx[slot];
    const int row = (int)(idx >> 8), col = (int)(idx & 255u);
    const double ry = cand_ry[slot], rx = cand_rx[slot];
    cyg[r] = ((double)row + 0.5) + ry;
    cxg[r] = ((double)col + 0.5) + rx;
    kept[r] = 1; nbrc[r] = 0;
    cellrank[idx] = (unsigned int)r;
    atomicMax(&sh_maxreg, __float_as_int((float)fabs(ry)));
    atomicMax(&sh_maxreg, __float_as_int((float)fabs(rx)));
  }
  __syncthreads();
  const float maxreg = __int_as_float(sh_maxreg);
  int rad = (int)(1.0f + 2.0f * maxreg) + 1;
  if (rad > 8) rad = 8;
  if (rad < 1) rad = 1;

  // ---- earlier-close neighbor lists into LDS (f64 distances)
  for (int r = tid; r < KTOP; r += 1024) {
    const unsigned int idx = cand_idx[si[r]];
    const int row = (int)(idx >> 8), col = (int)(idx & 255u);
    int n = 0;
    const double pyr = cyg[r], pxr = cxg[r];
    for (int dy = -rad; dy <= rad; ++dy) {
      const int yy = row + dy; if (yy < 0 || yy >= 256) continue;
      for (int dx = -rad; dx <= rad; ++dx) {
        if (dy == 0 && dx == 0) continue;
        const int xx = col + dx; if (xx < 0 || xx >= 256) continue;
        const unsigned int q = cellrank[yy * 256 + xx];
        if (q < (unsigned int)r) {
          const double t1 = __dsub_rn(pyr, cyg[q]);
          const double t2 = __dsub_rn(pxr, cxg[q]);
          const double d2 = __dadd_rn(__dmul_rn(t1, t1), __dmul_rn(t2, t2));
          if (d2 < 1.0) { if (n < 16) nbrs[(r << 4) + n] = (unsigned short)q; ++n; }
        }
      }
    }
    nbrc[r] = (unsigned char)(n < 16 ? n : 16);
  }
  __syncthreads();

  // ---- fixpoint == sequential NMS (unique fixpoint on rank-DAG), LDS-only
  for (int it = 0; it < 4096; ++it) {
    __syncthreads();
    if (tid == 0) changed = 0;
    __syncthreads();
    for (int r = tid; r < KTOP; r += 1024) {
      const int nc = nbrc[r];
      if (nc) {
        int kvv = 1;
        for (int t = 0; t < nc; ++t)
          if (kept[nbrs[(r << 4) + t]]) { kvv = 0; break; }
        if (kvv != (int)kept[r]) { kept[r] = (unsigned char)kvv; changed = 1; }
      }
    }
    __syncthreads();
    if (changed == 0) break;
  }

  // ---- inclusive prefix scan of kept
  scan[tid]        = (tid < KTOP) ? (int)kept[tid] : 0;
  scan[tid + 1024] = (tid + 1024 < KTOP) ? (int)kept[tid + 1024] : 0;
  __syncthreads();
  for (int off = 1; off < 2048; off <<= 1) {
    const int a0 = scan[tid];
    const int b0 = (tid >= off) ? scan[tid - off] : 0;
    const int a1 = scan[tid + 1024];
    const int b1 = (tid + 1024 >= off) ? scan[tid + 1024 - off] : 0;
    __syncthreads();
    scan[tid] = a0 + b0;
    scan[tid + 1024] = a1 + b1;
    __syncthreads();
  }
  const int total = scan[KTOP - 1];

  // ---- emit
  for (int r = tid; r < KTOP; r += 1024) {
    int slot = -1;
    if (kept[r]) { const int p = scan[r] - 1; if (p < MAXOUT) slot = p; }
    else { const int p = total + (r - scan[r]); if (p < MAXOUT) slot = p; }
    if (slot >= 0) {
      const double sg = __longlong_as_double((long long)sk[r]);
      out_ps[slot] = kept[r] ? (float)sg : -1.0f;
      const double py = cyg[r], px = cxg[r];
      out_dec[slot * 2]     = (float)(py * 4.0);
      out_dec[slot * 2 + 1] = (float)(px * 4.0);
      int sy = (int)rint(py * 2.0 - 24.0);
      int sx = (int)rint(px * 2.0 - 24.0);
      sy = sy < 0 ? 0 : (sy > 464 ? 464 : sy);
      sx = sx < 0 ? 0 : (sx > 464 ? 464 : sx);
      startb[slot * 2] = sy; startb[slot * 2 + 1] = sx;
    }
  }
}

// ---------------------------------------------------------------------------
// conv_i via bf16 MFMA: 3x3 32->64 + relu on 48x48 crops -> h (bf16).
// ---------------------------------------------------------------------------
#define ISTR 40   // input pixel stride in bf16 elems (80 B)
__global__ __launch_bounds__(256) void conv_i_mfma(
    const float* __restrict__ seg, const unsigned short* __restrict__ WiB,
    const float* __restrict__ bi, const int* __restrict__ startb,
    unsigned short* __restrict__ h, int inst0)
{
  __shared__ __align__(16) unsigned short ins[500 * ISTR];   // 40 KB (reused)
  const int li = blockIdx.y;
  const int inst = inst0 + li;
  const int tile = blockIdx.x;              // 0..5
  const int r0 = tile << 3;
  const int tid = threadIdx.x;
  const int sy = startb[inst * 2], sx = startb[inst * 2 + 1];

  for (int p = tid; p < 500; p += 256) {
    const int rr = p / 50, cc2 = p - rr * 50;
    const int ir = r0 - 1 + rr, ic = cc2 - 1;
    unsigned short* dst = &ins[p * ISTR];
    if (ir >= 0 && ir < 48 && ic >= 0 && ic < 48) {
      const float* src = &seg[((size_t)(sy + ir) * 512 + (sx + ic)) * 32];
#pragma unroll
      for (int q = 0; q < 8; ++q) {
        const float4 v = *(const float4*)&src[q << 2];
        const unsigned int lo = (unsigned int)f2bf(v.x) | ((unsigned int)f2bf(v.y) << 16);
        const unsigned int hi = (unsigned int)f2bf(v.z) | ((unsigned int)f2bf(v.w) << 16);
        *(uint2*)&dst[q << 2] = make_uint2(lo, hi);
      }
    } else {
#pragma unroll
      for (int q = 0; q < 4; ++q) *(uint4*)&dst[q << 3] = make_uint4(0, 0, 0, 0);
    }
  }
  __syncthreads();

  const int wv = tid >> 6, lane = tid & 63;
  const int l15 = lane & 15, quad = lane >> 4;
  const int wmb = wv * 96;

  int pbase[6];
#pragma unroll
  for (int i = 0; i < 6; ++i) {
    const int m = wmb + (i << 4) + l15;
    pbase[i] = (m / 48 + 1) * 50 + (m % 48) + 1;
  }

  f32x4 acc[6][4];
  const f32x4 z4 = {0.f, 0.f, 0.f, 0.f};
#pragma unroll
  for (int i = 0; i < 6; ++i)
#pragma unroll
    for (int j = 0; j < 4; ++j) acc[i][j] = z4;

  for (int tap = 0; tap < 9; ++tap) {
    const int off = (tap / 3 - 1) * 50 + (tap % 3 - 1);
    short8 b[4];
#pragma unroll
    for (int j = 0; j < 4; ++j)
      b[j] = *(const short8*)&WiB[((tap << 6) + (j << 4) + l15) * 32 + (quad << 3)];
#pragma unroll
    for (int i = 0; i < 6; ++i) {
      const short8 a = *(const short8*)&ins[(pbase[i] + off) * ISTR + (quad << 3)];
#pragma unroll
      for (int j = 0; j < 4; ++j)
        acc[i][j] = __builtin_amdgcn_mfma_f32_16x16x32_bf16(a, b[j], acc[i][j], 0, 0, 0);
    }
  }

  float bv[4];
#pragma unroll
  for (int j = 0; j < 4; ++j) bv[j] = bi[(j << 4) + l15];

  for (int half = 0; half < 2; ++half) {
    __syncthreads();
    if ((wv >> 1) == half) {
#pragma unroll
      for (int i = 0; i < 6; ++i)
#pragma unroll
        for (int j = 0; j < 4; ++j)
#pragma unroll
          for (int rg = 0; rg < 4; ++rg) {
            const int m = wmb + (i << 4) + (quad << 2) + rg;
            const int pp = m - half * 192;
            const float v = fmaxf(acc[i][j][rg] + bv[j], 0.f);
            ins[pp * 72 + (j << 4) + l15] = f2bf(v);
          }
    }
    __syncthreads();
    for (int t = tid; t < 192 * 8; t += 256) {
      const int pp = t >> 3, c8 = t & 7;
      const uint4 v = *(const uint4*)&ins[pp * 72 + (c8 << 3)];
      *(uint4*)&h[((size_t)li * 2304 + (tile * 384 + half * 192 + pp)) * 64 + (c8 << 3)] = v;
    }
  }
}

// ---------------------------------------------------------------------------
// conv_o: 3x3, 64->1 + sigmoid on bf16 h; emits instance_coords.
// ---------------------------------------------------------------------------
__global__ __launch_bounds__(256) void conv_o_kernel(
    const unsigned short* __restrict__ h, const float* __restrict__ Wo,
    const float* __restrict__ bo, const int* __restrict__ startb,
    float* __restrict__ out_io, float* __restrict__ out_ic, int inst0)
{
  __shared__ __align__(16) unsigned short hs[324 * 72];   // 46.7 KB
  __shared__ float wos[576];
  const int li = blockIdx.y;
  const int inst = inst0 + li;
  const int tile = blockIdx.x;
  const int ty0 = (tile / 3) << 4;
  const int tx0 = (tile % 3) << 4;
  const int tid = threadIdx.x;

  for (int i = tid; i < 576; i += 256) wos[i] = Wo[i];
  for (int p = tid; p < 324; p += 256) {
    const int iy = p / 18, ix = p - iy * 18;
    const int gy = ty0 - 1 + iy, gx = tx0 - 1 + ix;
    unsigned short* dst = &hs[p * 72];
    if (gy >= 0 && gy < 48 && gx >= 0 && gx < 48) {
      const unsigned short* src = &h[((size_t)li * 2304 + gy * 48 + gx) * 64];
#pragma unroll
      for (int q = 0; q < 8; ++q) *(uint4*)&dst[q << 3] = *(const uint4*)&src[q << 3];
    } else {
#pragma unroll
      for (int q = 0; q < 8; ++q) *(uint4*)&dst[q << 3] = make_uint4(0, 0, 0, 0);
    }
  }
  __syncthreads();

  const int ly = tid >> 4, lx = tid & 15;
  float a = 0.f;
#pragma unroll
  for (int ky = 0; ky < 3; ++ky)
#pragma unroll
    for (int kx = 0; kx < 3; ++kx) {
      const unsigned short* hp = &hs[((ly + ky) * 18 + lx + kx) * 72];
      const float* wp = &wos[(ky * 3 + kx) << 6];
#pragma unroll
      for (int c8 = 0; c8 < 8; ++c8) {
        const uint4 hv = *(const uint4*)&hp[c8 << 3];
        const unsigned int uu[4] = {hv.x, hv.y, hv.z, hv.w};
#pragma unroll
        for (int e = 0; e < 4; ++e) {
          const float f0 = __uint_as_float(uu[e] << 16);
          const float f1 = __uint_as_float(uu[e] & 0xFFFF0000u);
          a = fmaf(f0, wp[(c8 << 3) + (e << 1)], a);
          a = fmaf(f1, wp[(c8 << 3) + (e << 1) + 1], a);
        }
      }
    }
  a += bo[0];
  const float o = 1.f / (1.f + expf(-a));
  const int gy = ty0 + ly, gx = tx0 + lx;
  const size_t p = ((size_t)inst * 48 + gy) * 48 + gx;
  out_io[p] = o;
  const int sy = startb[inst * 2], sx = startb[inst * 2 + 1];
  out_ic[p * 2]     = (float)(sy + gy);
  out_ic[p * 2 + 1] = (float)(sx + gx);
}

// ---------------------------------------------------------------------------
extern "C" void kernel_launch(void* const* d_in, const int* in_sizes, int n_in,
                              void* d_out, int out_size, void* d_ws, size_t ws_size,
                              hipStream_t stream)
{
  const float* df  = (const float*)d_in[0];
  const float* seg = (const float*)d_in[1];
  const float* Wc  = (const float*)d_in[2];
  const float* bc  = (const float*)d_in[3];
  const float* Wfc = (const float*)d_in[4];
  const float* bfc = (const float*)d_in[5];
  const float* Wsc = (const float*)d_in[6];
  const float* bs  = (const float*)d_in[7];
  const float* Wrg = (const float*)d_in[8];
  const float* br  = (const float*)d_in[9];
  const float* Wi  = (const float*)d_in[10];
  const float* bi  = (const float*)d_in[11];
  const float* Wo  = (const float*)d_in[12];
  const float* bo  = (const float*)d_in[13];

  const size_t SZ_WCT = 2359296ull, SZ_WFT = 2097152ull, SZ_WIB = 36864ull,
               SZ_DFB = 17040384ull,                      // 258*258*128 bf16
               SZ_PART = 2097152ull, SZ_SC = 262144ull, SZ_CR = 262144ull,
               SZ_STB = 4096ull, SZ_CI = CANDCAP * 4ull,
               SZ_SB = CANDCAP * 8ull, SZ_RY = CANDCAP * 8ull,
               SZ_RX = CANDCAP * 8ull, SZ_CY = 16384ull, SZ_CX = 16384ull,
               SZ_X1G = (size_t)CANDCAP * 1024ull * 8ull,   // 33.5 MB, own slot
               SZ_CNT = 256ull;
  const size_t FIXED = SZ_WCT + SZ_WFT + SZ_WIB + SZ_DFB + SZ_PART + SZ_SC +
                       SZ_CR + SZ_STB + SZ_CI + SZ_SB + SZ_RY + SZ_RX +
                       SZ_CY + SZ_CX + SZ_X1G + SZ_CNT;
  char* w = (char*)d_ws;
  size_t region = (ws_size > FIXED) ? ((ws_size - FIXED) & ~(size_t)255) : 0;
  char* fb = w + region;
  unsigned short* WcT = (unsigned short*)fb;   fb += SZ_WCT;
  unsigned short* WfcT = (unsigned short*)fb;  fb += SZ_WFT;
  unsigned short* WiB = (unsigned short*)fb;   fb += SZ_WIB;
  unsigned short* dfb = (unsigned short*)fb;   fb += SZ_DFB;
  float* part = (float*)fb;                    fb += SZ_PART;
  float* scores = (float*)fb;                  fb += SZ_SC;
  unsigned int* cellrank = (unsigned int*)fb;  fb += SZ_CR;
  int* startb = (int*)fb;                      fb += SZ_STB;
  unsigned int* cand_idx = (unsigned int*)fb;  fb += SZ_CI;
  unsigned long long* cand_sb = (unsigned long long*)fb; fb += SZ_SB;
  double* cand_ry = (double*)fb;               fb += SZ_RY;
  double* cand_rx = (double*)fb;               fb += SZ_RX;
  double* cyg = (double*)fb;                   fb += SZ_CY;
  double* cxg = (double*)fb;                   fb += SZ_CX;
  double* x1g = (double*)fb;                   fb += SZ_X1G;
  unsigned int* cand_cnt = (unsigned int*)fb;
  unsigned short* x1b = (unsigned short*)w;    // big region: bf16 x1 chunk
  unsigned short* hb = (unsigned short*)w;     // big region: bf16 inst crops

  size_t tiles_fit = region / 131072ull;
  int pt_chunk = 4;                            // 256-row tiles need mult of 4
  while ((size_t)(pt_chunk * 2) <= tiles_fit && pt_chunk < 1024) pt_chunk <<= 1;
  size_t inst_fit = region / 294912ull;        // 48*48*64*2B per instance
  const int opts[12] = {500, 250, 125, 100, 50, 25, 20, 10, 5, 4, 2, 1};
  int inst_chunk = 1;
  for (int o = 0; o < 12; ++o)
    if ((size_t)opts[o] <= inst_fit) { inst_chunk = opts[o]; break; }

  float* out = (float*)d_out;
  float* out_ps  = out;
  float* out_dec = out + 500;
  float* out_io  = out + 1500;
  float* out_ic  = out + 1153500;

  transpose_bf16_kernel<<<dim3(36, 32), 256, 0, stream>>>(Wc, WcT, 1152, 1024);
  transpose_bf16_kernel<<<dim3(32, 32), 256, 0, stream>>>(Wfc, WfcT, 1024, 1024);
  prep_wib_kernel<<<72, 256, 0, stream>>>(Wi, WiB);
  pad_df_bf16<<<4161, 256, 0, stream>>>(df, dfb);

  for (int c = 0; c < 1024 / pt_chunk; ++c) {
    conv1_mfma<<<dim3(4, pt_chunk / 4), 512, 0, stream>>>(dfb, WcT, bc, x1b,
                                                          c * pt_chunk);
    fc_mfma<<<dim3(4, pt_chunk / 4), 512, 0, stream>>>(x1b, WfcT, bfc, Wsc,
                                                       part, c * pt_chunk);
  }
  head_finalize_kernel<<<256, 256, 0, stream>>>(part, bs, scores);
  select_kernel<<<1, 1024, 0, stream>>>(scores, cand_idx, cand_cnt);
  rescore_conv<<<(CANDCAP / RCC) * 2, 512, 0, stream>>>(df, Wc, bc, cand_idx,
                                                        cand_cnt, x1g);
  rescore_fc<<<CANDCAP / RC2, 512, 0, stream>>>(x1g, Wfc, bfc, Wsc, bs, Wrg,
                                                br, cand_cnt, cand_sb,
                                                cand_ry, cand_rx);
  proposal_kernel<<<1, 1024, PROP_LDS, stream>>>(cand_idx, cand_cnt, cand_sb,
                                                 cand_ry, cand_rx, cellrank,
                                                 cyg, cxg, startb, out_ps,
                                                 out_dec);
  for (int c = 0; c < 500 / inst_chunk; ++c) {
    conv_i_mfma<<<dim3(6, inst_chunk), 256, 0, stream>>>(seg, WiB, bi, startb,
                                                         hb, c * inst_chunk);
    conv_o_kernel<<<dim3(9, inst_chunk), 256, 0, stream>>>(hb, Wo, bo, startb,
                                                           out_io, out_ic,
                                                           c * inst_chunk);
  }
}

// Round 8
// 1119.799 us; speedup vs baseline: 1.0440x; 1.0440x over previous
//
#include <hip/hip_runtime.h>
#include <math.h>

#define KTOP 2000
#define MAXOUT 500
#define CANDCAP 4096          // candidate capacity (global buffers)
#define NSEL 3600             // approx-score rank margin for selection
#define RCC 32                // candidates per rescore_conv block (N-split x2)
#define RC2 16                // candidates per rescore_fc block

typedef __attribute__((ext_vector_type(8))) short short8;
typedef __attribute__((ext_vector_type(4))) float f32x4;
typedef __attribute__((ext_vector_type(4))) double f64x4;

__device__ __forceinline__ unsigned short f2bf(float f) {
  unsigned int u = __float_as_uint(f);
  unsigned int r = ((u >> 16) & 1u) + 0x7FFFu;
  return (unsigned short)((u + r) >> 16);
}

__device__ __forceinline__ void ld_lds16(const void* g, void* l) {
  __builtin_amdgcn_global_load_lds((const unsigned int*)g, (unsigned int*)l,
                                   16, 0, 0);
}

// raw barrier that does NOT drain vmcnt, with compiler+scheduler fences
__device__ __forceinline__ void hard_barrier() {
  asm volatile("" ::: "memory");
  __builtin_amdgcn_sched_barrier(0);
  __builtin_amdgcn_s_barrier();
  __builtin_amdgcn_sched_barrier(0);
  asm volatile("" ::: "memory");
}

// ---------------------------------------------------------------------------
// transpose+convert: W[K][N] f32 -> WT[N][K] bf16.  grid (K/32, N/32), 256 thr
// ---------------------------------------------------------------------------
__global__ __launch_bounds__(256) void transpose_bf16_kernel(
    const float* __restrict__ W, unsigned short* __restrict__ WT, int K, int N)
{
  __shared__ float t[32][33];
  const int k0 = blockIdx.x << 5, n0 = blockIdx.y << 5;
  const int tid = threadIdx.x;
  const int r = tid >> 5, c = tid & 31;
#pragma unroll
  for (int p = 0; p < 4; ++p)
    t[r + (p << 3)][c] = W[(size_t)(k0 + r + (p << 3)) * N + n0 + c];
  __syncthreads();
#pragma unroll
  for (int p = 0; p < 4; ++p)
    WT[(size_t)(n0 + r + (p << 3)) * K + k0 + c] = f2bf(t[c][r + (p << 3)]);
}

// ---------------------------------------------------------------------------
// prep WiB: Wi[288][64] f32 -> WiB[tap(9)][co(64)][ci(32)] bf16
// ---------------------------------------------------------------------------
__global__ __launch_bounds__(256) void prep_wib_kernel(
    const float* __restrict__ Wi, unsigned short* __restrict__ WiB)
{
  const int t = blockIdx.x * 256 + threadIdx.x;
  if (t < 9 * 64 * 32) {
    const int tap = t / 2048, r = t & 2047, co = r >> 5, ci = r & 31;
    WiB[t] = f2bf(Wi[((size_t)tap * 32 + ci) * 64 + co]);
  }
}

// ---------------------------------------------------------------------------
// pad+convert df: [256][256][128] f32 -> [258][258][128] bf16 with zero halo.
// ---------------------------------------------------------------------------
__global__ __launch_bounds__(256) void pad_df_bf16(
    const float* __restrict__ df, unsigned short* __restrict__ dfb)
{
  const int t = blockIdx.x * 256 + threadIdx.x;
  if (t >= 258 * 258 * 16) return;
  const int p = t >> 4;              // padded pixel id
  const int c8 = (t & 15) << 3;      // channel base
  const int gy = p / 258 - 1, gx = p % 258 - 1;
  uint4 out = make_uint4(0, 0, 0, 0);
  if (gy >= 0 && gy < 256 && gx >= 0 && gx < 256) {
    const float* src = &df[((size_t)(gy * 256 + gx)) * 128 + c8];
    const float4 v0 = *(const float4*)src;
    const float4 v1 = *(const float4*)(src + 4);
    out.x = (unsigned int)f2bf(v0.x) | ((unsigned int)f2bf(v0.y) << 16);
    out.y = (unsigned int)f2bf(v0.z) | ((unsigned int)f2bf(v0.w) << 16);
    out.z = (unsigned int)f2bf(v1.x) | ((unsigned int)f2bf(v1.y) << 16);
    out.w = (unsigned int)f2bf(v1.z) | ((unsigned int)f2bf(v1.w) << 16);
  }
  *(uint4*)&dfb[(size_t)p * 128 + c8] = out;
}

// ---------------------------------------------------------------------------
// 8-phase 256x256x64 K-tile body: 4 quadrant phases, minimal ds_read reuse
// (A held across nh-phases, both B halves held), setprio around MFMA.
// The next-tile global_load_lds issues are injected after phase 2's trailing
// barrier (all reads of this buffer complete there; phase 3 is pure-register)
// so phase 3's MFMA hides the issue cost.
// ---------------------------------------------------------------------------
template <typename IssueFn>
__device__ __forceinline__ void ktile_phases(
    const unsigned short* __restrict__ A0, const unsigned short* __restrict__ B0,
    const int arow, const int brow, const int ok0, const int ok1,
    f32x4 (&acc)[8][4], IssueFn&& iss, const bool do_issue)
{
  short8 Af[4][2], Bf[2][2][2];
  // ---- phase 0: read A(mh=0) + B(nh=0); MFMA Q(0,0)
#pragma unroll
  for (int m = 0; m < 4; ++m) {
    Af[m][0] = *(const short8*)&A0[((arow + (m << 4)) << 6) + ok0];
    Af[m][1] = *(const short8*)&A0[((arow + (m << 4)) << 6) + ok1];
  }
#pragma unroll
  for (int n = 0; n < 2; ++n) {
    Bf[0][n][0] = *(const short8*)&B0[((brow + (n << 4)) << 6) + ok0];
    Bf[0][n][1] = *(const short8*)&B0[((brow + (n << 4)) << 6) + ok1];
  }
  hard_barrier();
  __builtin_amdgcn_s_setprio(1);
#pragma unroll
  for (int m = 0; m < 4; ++m)
#pragma unroll
    for (int n = 0; n < 2; ++n) {
      acc[m][n] = __builtin_amdgcn_mfma_f32_16x16x32_bf16(Af[m][0], Bf[0][n][0], acc[m][n], 0, 0, 0);
      acc[m][n] = __builtin_amdgcn_mfma_f32_16x16x32_bf16(Af[m][1], Bf[0][n][1], acc[m][n], 0, 0, 0);
    }
  __builtin_amdgcn_s_setprio(0);
  hard_barrier();
  // ---- phase 1: read B(nh=1); MFMA Q(0,1)
#pragma unroll
  for (int n = 0; n < 2; ++n) {
    Bf[1][n][0] = *(const short8*)&B0[((brow + ((n + 2) << 4)) << 6) + ok0];
    Bf[1][n][1] = *(const short8*)&B0[((brow + ((n + 2) << 4)) << 6) + ok1];
  }
  hard_barrier();
  __builtin_amdgcn_s_setprio(1);
#pragma unroll
  for (int m = 0; m < 4; ++m)
#pragma unroll
    for (int n = 0; n < 2; ++n) {
      acc[m][n + 2] = __builtin_amdgcn_mfma_f32_16x16x32_bf16(Af[m][0], Bf[1][n][0], acc[m][n + 2], 0, 0, 0);
      acc[m][n + 2] = __builtin_amdgcn_mfma_f32_16x16x32_bf16(Af[m][1], Bf[1][n][1], acc[m][n + 2], 0, 0, 0);
    }
  __builtin_amdgcn_s_setprio(0);
  hard_barrier();
  // ---- phase 2: read A(mh=1); MFMA Q(1,1)
#pragma unroll
  for (int m = 0; m < 4; ++m) {
    Af[m][0] = *(const short8*)&A0[((arow + 64 + (m << 4)) << 6) + ok0];
    Af[m][1] = *(const short8*)&A0[((arow + 64 + (m << 4)) << 6) + ok1];
  }
  hard_barrier();
  __builtin_amdgcn_s_setprio(1);
#pragma unroll
  for (int m = 0; m < 4; ++m)
#pragma unroll
    for (int n = 0; n < 2; ++n) {
      acc[m + 4][n + 2] = __builtin_amdgcn_mfma_f32_16x16x32_bf16(Af[m][0], Bf[1][n][0], acc[m + 4][n + 2], 0, 0, 0);
      acc[m + 4][n + 2] = __builtin_amdgcn_mfma_f32_16x16x32_bf16(Af[m][1], Bf[1][n][1], acc[m + 4][n + 2], 0, 0, 0);
    }
  __builtin_amdgcn_s_setprio(0);
  hard_barrier();
  // all LDS reads of this buffer complete; issue next-tile loads here so
  // phase 3's MFMA hides them.
  if (do_issue) iss();
  // ---- phase 3: no reads; MFMA Q(1,0) with held Bf[0]
  __builtin_amdgcn_s_setprio(1);
#pragma unroll
  for (int m = 0; m < 4; ++m)
#pragma unroll
    for (int n = 0; n < 2; ++n) {
      acc[m + 4][n] = __builtin_amdgcn_mfma_f32_16x16x32_bf16(Af[m][0], Bf[0][n][0], acc[m + 4][n], 0, 0, 0);
      acc[m + 4][n] = __builtin_amdgcn_mfma_f32_16x16x32_bf16(Af[m][1], Bf[0][n][1], acc[m + 4][n], 0, 0, 0);
    }
  __builtin_amdgcn_s_setprio(0);
  hard_barrier();
}

// ---------------------------------------------------------------------------
// conv1: 3x3 128->1024 + bias + relu -> x1b.  256x256 tile, BK=64, 8 waves,
// 8-phase schedule, counted vmcnt(8) double-buffered global_load_lds.
// ---------------------------------------------------------------------------
__global__ __launch_bounds__(512) void conv1_mfma(
    const unsigned short* __restrict__ dfb, const unsigned short* __restrict__ WcT,
    const float* __restrict__ bc, unsigned short* __restrict__ x1b, int pt0)
{
  __shared__ __align__(16) unsigned short smem[65536];   // 128 KB
  const int tid = threadIdx.x;
  const int wv = tid >> 6, lane = tid & 63;
  const int wr = wv >> 2, wc = wv & 3;
  const int l15 = lane & 15, quad = lane >> 4;
  const int n0 = blockIdx.x << 8;
  const int lm0 = blockIdx.y << 8;
  const int Pbase = (pt0 << 6) + lm0;   // multiple of 256
  const int y = Pbase >> 8;
  const int tr = tid >> 3, g8 = tid & 7;
  const int xg = ((g8 ^ (tr & 7)) << 4);           // swizzled source byte off
  const int axr = l15 & 7;
  const int ok0 = ((quad ^ axr) << 3);
  const int ok1 = (((4 + quad) ^ axr) << 3);
  const int arow = (wr << 7) + l15;
  const int brow = (wc << 6) + l15;

  // preload bias BEFORE any global_load_lds (keeps vmcnt counting exact)
  float bcv[4];
#pragma unroll
  for (int j = 0; j < 4; ++j) bcv[j] = bc[n0 + (wc << 6) + (j << 4) + l15];

  f32x4 acc[8][4];
  const f32x4 z4 = {0.f, 0.f, 0.f, 0.f};
#pragma unroll
  for (int i = 0; i < 8; ++i)
#pragma unroll
    for (int j = 0; j < 4; ++j) acc[i][j] = z4;

  const char* WB = (const char*)WcT + ((size_t)(n0 + tr) * 1152) * 2 + xg;
  unsigned short* lA = &smem[(tr << 6) + (g8 << 3)];

  auto issue = [&](int kt, int buf) {
    const int tap = kt >> 1, ci0 = (kt & 1) << 6;
    const int dy = tap / 3 - 1, dx = tap % 3 - 1;
    const char* Ab = (const char*)dfb +
        (((size_t)((y + dy + 1) * 258 + dx + 1)) * 128 + ci0) * 2 +
        (size_t)tr * 256 + xg;
    unsigned short* la = lA + buf * 32768;
    unsigned short* lb = la + 16384;
    const char* Bb = WB + (size_t)kt * 128;
#pragma unroll
    for (int i = 0; i < 4; ++i)
      ld_lds16(Ab + (size_t)i * 16384, la + i * 4096);
#pragma unroll
    for (int i = 0; i < 4; ++i)
      ld_lds16(Bb + (size_t)i * 147456, lb + i * 4096);
  };

  issue(0, 0);
  issue(1, 1);
#pragma unroll 2
  for (int kt = 0; kt < 18; ++kt) {
    const int buf = kt & 1;
    if (kt < 17) asm volatile("s_waitcnt vmcnt(8)" ::: "memory");
    else         asm volatile("s_waitcnt vmcnt(0)" ::: "memory");
    hard_barrier();
    ktile_phases(&smem[buf * 32768], &smem[buf * 32768 + 16384],
                 arow, brow, ok0, ok1, acc,
                 [&]() { issue(kt + 2, buf); }, kt < 16);
  }

#pragma unroll
  for (int m = 0; m < 8; ++m)
#pragma unroll
    for (int n = 0; n < 4; ++n) {
      const int col = n0 + (wc << 6) + (n << 4) + l15;
      const float bb = bcv[n];
#pragma unroll
      for (int rg = 0; rg < 4; ++rg) {
        const int row = lm0 + (wr << 7) + (m << 4) + (quad << 2) + rg;
        const float v = fmaxf(acc[m][n][rg] + bb, 0.f);
        x1b[(size_t)row * 1024 + col] = f2bf(v);
      }
    }
}

// ---------------------------------------------------------------------------
// fc: 1x1 1024->1024 + bias + relu, fused score partials.  Same 8-phase
// structure; partial written per N-block (4 chunks).
// ---------------------------------------------------------------------------
__global__ __launch_bounds__(512) void fc_mfma(
    const unsigned short* __restrict__ x1b, const unsigned short* __restrict__ WfcT,
    const float* __restrict__ bfc, const float* __restrict__ Wsc,
    float* __restrict__ part, int pt0)
{
  __shared__ __align__(16) unsigned short smem[65536];   // 128 KB
  const int tid = threadIdx.x;
  const int wv = tid >> 6, lane = tid & 63;
  const int wr = wv >> 2, wc = wv & 3;
  const int l15 = lane & 15, quad = lane >> 4;
  const int n0 = blockIdx.x << 8;
  const int lm0 = blockIdx.y << 8;
  const int Pbase = (pt0 << 6) + lm0;
  const int tr = tid >> 3, g8 = tid & 7;
  const int xg = ((g8 ^ (tr & 7)) << 4);
  const int axr = l15 & 7;
  const int ok0 = ((quad ^ axr) << 3);
  const int ok1 = (((4 + quad) ^ axr) << 3);
  const int arow = (wr << 7) + l15;
  const int brow = (wc << 6) + l15;

  float wsv[4], bfv[4];
#pragma unroll
  for (int j = 0; j < 4; ++j) {
    const int col = n0 + (wc << 6) + (j << 4) + l15;
    wsv[j] = Wsc[col];
    bfv[j] = bfc[col];
  }

  f32x4 acc[8][4];
  const f32x4 z4 = {0.f, 0.f, 0.f, 0.f};
#pragma unroll
  for (int i = 0; i < 8; ++i)
#pragma unroll
    for (int j = 0; j < 4; ++j) acc[i][j] = z4;

  const char* AB = (const char*)x1b + ((size_t)(lm0 + tr) * 1024) * 2 + xg;
  const char* WB = (const char*)WfcT + ((size_t)(n0 + tr) * 1024) * 2 + xg;
  unsigned short* lA = &smem[(tr << 6) + (g8 << 3)];

  auto issue = [&](int kt, int buf) {
    unsigned short* la = lA + buf * 32768;
    unsigned short* lb = la + 16384;
    const char* Ab = AB + (size_t)kt * 128;
    const char* Bb = WB + (size_t)kt * 128;
#pragma unroll
    for (int i = 0; i < 4; ++i)
      ld_lds16(Ab + (size_t)i * 131072, la + i * 4096);
#pragma unroll
    for (int i = 0; i < 4; ++i)
      ld_lds16(Bb + (size_t)i * 131072, lb + i * 4096);
  };

  issue(0, 0);
  issue(1, 1);
#pragma unroll 2
  for (int kt = 0; kt < 16; ++kt) {
    const int buf = kt & 1;
    if (kt < 15) asm volatile("s_waitcnt vmcnt(8)" ::: "memory");
    else         asm volatile("s_waitcnt vmcnt(0)" ::: "memory");
    hard_barrier();
    ktile_phases(&smem[buf * 32768], &smem[buf * 32768 + 16384],
                 arow, brow, ok0, ok1, acc,
                 [&]() { issue(kt + 2, buf); }, kt < 14);
  }

  // fused score partial: per row, sum over this block's 256 cols
  float* red = (float*)smem;    // 256*5 floats
#pragma unroll
  for (int m = 0; m < 8; ++m)
#pragma unroll
    for (int rg = 0; rg < 4; ++rg) {
      float ps = 0.f;
#pragma unroll
      for (int n = 0; n < 4; ++n) {
        const float v = fmaxf(acc[m][n][rg] + bfv[n], 0.f);
        ps = fmaf(v, wsv[n], ps);
      }
      // butterfly over the 16 l15 lanes (stays within quad group)
#pragma unroll
      for (int off = 1; off <= 8; off <<= 1)
        ps += __shfl_xor(ps, off, 64);
      if (l15 == 0) {
        const int row = (wr << 7) + (m << 4) + (quad << 2) + rg;
        red[row * 5 + wc] = ps;
      }
    }
  __syncthreads();
  if (tid < 256) {
    float s = 0.f;
#pragma unroll
    for (int w8 = 0; w8 < 4; ++w8) s += red[tid * 5 + w8];
    part[(size_t)blockIdx.x * 65536 + Pbase + tid] = s;
  }
}

// ---------------------------------------------------------------------------
// finalize: sum 4 partials, bias, sigmoid -> f32 approx scores (selection)
// ---------------------------------------------------------------------------
__global__ __launch_bounds__(256) void head_finalize_kernel(
    const float* __restrict__ part, const float* __restrict__ bs,
    float* __restrict__ scores)
{
  const int pix = blockIdx.x * 256 + threadIdx.x;
  float s = 0.f;
#pragma unroll
  for (int cb = 0; cb < 4; ++cb) s += part[(size_t)cb * 65536 + pix];
  s += bs[0];
  scores[pix] = 1.f / (1.f + expf(-s));
}

// ---------------------------------------------------------------------------
// select: radix-select NSEL-th approx score (parallel suffix-scan bucket
// pick), then DETERMINISTIC prefix-scan compaction in ascending cell order.
// ---------------------------------------------------------------------------
__global__ __launch_bounds__(1024) void select_kernel(
    const float* __restrict__ scores, unsigned int* __restrict__ cand_idx,
    unsigned int* __restrict__ cand_cnt)
{
  __shared__ unsigned int hist[256];
  __shared__ unsigned int sh_prefix, sh_sub;
  __shared__ int scan_s[1024];
  const int tid = threadIdx.x;

  unsigned int prefix = 0u;
  int need = NSEL;
  for (int byte = 3; byte >= 0; --byte) {
    if (tid < 256) hist[tid] = 0u;
    __syncthreads();
    const int sh = byte * 8;
    const unsigned int mhi = (byte == 3) ? 0u : (0xFFFFFFFFu << (sh + 8));
    for (int i = tid; i < 65536; i += 1024) {
      const unsigned int b = __float_as_uint(scores[i]);
      if ((b & mhi) == prefix) atomicAdd(&hist[(b >> sh) & 255u], 1u);
    }
    __syncthreads();
    // in-place parallel suffix sum: hist[v] := sum_{v'>=v} hist[v']
    for (int off = 1; off < 256; off <<= 1) {
      unsigned int add = 0u;
      if (tid < 256 && tid + off < 256) add = hist[tid + off];
      __syncthreads();
      if (tid < 256) hist[tid] += add;
      __syncthreads();
    }
    if (tid < 256) {
      const unsigned int sv = hist[tid];
      const unsigned int above = (tid == 255) ? 0u : hist[tid + 1];
      if ((int)above < need && (int)sv >= need) {
        sh_prefix = prefix | ((unsigned)tid << sh);
        sh_sub = above;
      }
    }
    __syncthreads();
    prefix = sh_prefix;
    need -= (int)sh_sub;
    __syncthreads();
  }
  const float thr = __uint_as_float(prefix);

  // deterministic compaction: thread t owns cells [t*64, t*64+64)
  const int b0 = tid << 6;
  int my = 0;
  for (int k = 0; k < 64; ++k)
    if (scores[b0 + k] >= thr) ++my;
  scan_s[tid] = my;
  __syncthreads();
  for (int off = 1; off < 1024; off <<= 1) {
    const int a = scan_s[tid];
    const int b = (tid >= off) ? scan_s[tid - off] : 0;
    __syncthreads();
    scan_s[tid] = a + b;
    __syncthreads();
  }
  int pos = scan_s[tid] - my;     // exclusive prefix
  const int total = scan_s[1023];
  for (int k = 0; k < 64; ++k) {
    if (scores[b0 + k] >= thr) {
      if (pos < CANDCAP) cand_idx[pos] = (unsigned int)(b0 + k);
      ++pos;
    }
  }
  if (tid == 0)
    *cand_cnt = (unsigned int)(total > CANDCAP ? CANDCAP : total);
}

// ---------------------------------------------------------------------------
// rescore_conv via f64 MFMA: M=32 cand x N=512 co per block (N-split x2),
// K=1152.  512 thr, 8 waves.  Double-buffered patt with async-stage split
// (loads issued before MFMA section, LDS writes after) + depth-2 weight
// prefetch.  Accumulation order identical to previous version (bit-exact).
// ---------------------------------------------------------------------------
#define PSTR 133   // f64 LDS row stride (conflict-free for quad-strided b64)
__global__ __launch_bounds__(512) void rescore_conv(
    const float* __restrict__ df, const float* __restrict__ Wc,
    const float* __restrict__ bc,
    const unsigned int* __restrict__ cand_idx,
    const unsigned int* __restrict__ cand_cnt,
    double* __restrict__ x1g)
{
  __shared__ double patt[2][RCC * PSTR];   // 68 KB
  __shared__ int rrs[RCC], ccs[RCC];
  const int cnt = (int)*cand_cnt;
  const int nb = blockIdx.x & 1;
  const int c0 = (blockIdx.x >> 1) * RCC;
  if (c0 >= cnt) return;
  const int tid = threadIdx.x;
  const int wv = tid >> 6, lane = tid & 63;
  const int m = lane & 15, quad = lane >> 4;
  const int co_base = (nb << 9) + (wv << 6);

  if (tid < RCC) {
    const int slot = (c0 + tid < cnt) ? c0 + tid : c0;
    const unsigned int idx = cand_idx[slot];
    rrs[tid] = (int)(idx >> 8); ccs[tid] = (int)(idx & 255u);
  }
  __syncthreads();

  // per-thread staged elements: p = tid + j*512, j=0..7 (RCC*128/512 = 8)
  float sv[8];
  auto ldregs = [&](int tap) {
    const int dy = tap / 3 - 1, dx = tap % 3 - 1;
#pragma unroll
    for (int j = 0; j < 8; ++j) {
      const int p = tid + (j << 9);
      const int c = p >> 7, ci = p & 127;
      const int gy = rrs[c] + dy, gx = ccs[c] + dx;
      float v = 0.f;
      if (gy >= 0 && gy < 256 && gx >= 0 && gx < 256)
        v = df[((size_t)((gy << 8) + gx)) * 128 + ci];
      sv[j] = v;
    }
  };
  auto wrlds = [&](int b) {
#pragma unroll
    for (int j = 0; j < 8; ++j) {
      const int p = tid + (j << 9);
      const int c = p >> 7, ci = p & 127;
      patt[b][c * PSTR + ci] = (double)sv[j];
    }
  };

  f64x4 acc[2][4];
  const f64x4 z4 = {0.0, 0.0, 0.0, 0.0};
#pragma unroll
  for (int ct = 0; ct < 2; ++ct)
#pragma unroll
    for (int t = 0; t < 4; ++t) acc[ct][t] = z4;

  ldregs(0);
  wrlds(0);
  __syncthreads();
  int buf = 0;
  for (int tap = 0; tap < 9; ++tap) {
    if (tap < 8) ldregs(tap + 1);        // async: loads in flight over MFMA
    const float* wrow = &Wc[(size_t)(tap * 128 + quad) * 1024 + co_base + m];
    float wf[4], wn[4];
#pragma unroll
    for (int t = 0; t < 4; ++t) wf[t] = wrow[t << 4];
#pragma unroll
    for (int t = 0; t < 4; ++t) wn[t] = wrow[(size_t)4096 + (t << 4)];
    for (int k4 = 0; k4 < 32; ++k4) {
      float w2[4];
      if (k4 + 2 < 32) {
#pragma unroll
        for (int t = 0; t < 4; ++t)
          w2[t] = wrow[(size_t)((k4 + 2) << 2) * 1024 + (t << 4)];
      }
      const double a0 = patt[buf][m * PSTR + (k4 << 2) + quad];
      const double a1 = patt[buf][(16 + m) * PSTR + (k4 << 2) + quad];
#pragma unroll
      for (int t = 0; t < 4; ++t)
        acc[0][t] = __builtin_amdgcn_mfma_f64_16x16x4f64(a0, (double)wf[t], acc[0][t], 0, 0, 0);
#pragma unroll
      for (int t = 0; t < 4; ++t)
        acc[1][t] = __builtin_amdgcn_mfma_f64_16x16x4f64(a1, (double)wf[t], acc[1][t], 0, 0, 0);
      if (k4 + 1 < 32) {
#pragma unroll
        for (int t = 0; t < 4; ++t) wf[t] = wn[t];
      }
      if (k4 + 2 < 32) {
#pragma unroll
        for (int t = 0; t < 4; ++t) wn[t] = w2[t];
      }
    }
    if (tap < 8) wrlds(buf ^ 1);         // write-late; reads of buf^1 done
    __syncthreads();
    buf ^= 1;
  }
#pragma unroll
  for (int ct = 0; ct < 2; ++ct)
#pragma unroll
    for (int t = 0; t < 4; ++t) {
      const int co = co_base + (t << 4) + m;
      const double bb = (double)bc[co];
#pragma unroll
      for (int rg = 0; rg < 4; ++rg) {
        const int cand = (ct << 4) + (quad << 2) + rg;
        if (c0 + cand < cnt) {
          const double v = acc[ct][t][rg] + bb;
          x1g[(size_t)(c0 + cand) * 1024 + co] = v > 0.0 ? v : 0.0;
        }
      }
    }
}

// ---------------------------------------------------------------------------
// rescore_fc via f64 MFMA: M=16 cand, N=1024, K=1024; heads fused with
// deterministic butterfly + fixed-order wave combine.  512 thr.
// Double-buffered xbuf with async-stage split; depth-1 weight prefetch
// (depth-2 reverted: register pressure with wf[8]/wn[8]/w2[8] regressed).
// ---------------------------------------------------------------------------
__global__ __launch_bounds__(512) void rescore_fc(
    const double* __restrict__ x1g, const float* __restrict__ Wfc,
    const float* __restrict__ bfc, const float* __restrict__ Wsc,
    const float* __restrict__ bs, const float* __restrict__ Wrg,
    const float* __restrict__ br,
    const unsigned int* __restrict__ cand_cnt,
    unsigned long long* __restrict__ cand_sb,
    double* __restrict__ cand_ry, double* __restrict__ cand_rx)
{
  __shared__ double xbuf[2][16 * PSTR];   // 34 KB
  __shared__ double partw[3][8][16];      // [head][wave][cand], 3 KB
  const int cnt = (int)*cand_cnt;
  const int c0 = blockIdx.x * RC2;
  if (c0 >= cnt) return;
  const int tid = threadIdx.x;
  const int wv = tid >> 6, lane = tid & 63;
  const int m = lane & 15, quad = lane >> 4;
  const int co_base = wv << 7;

  // per-thread staged elements: p = tid + j*512, j=0..3 (16*128/512 = 4)
  double sx[4];
  auto ldregs = [&](int kc) {
#pragma unroll
    for (int j = 0; j < 4; ++j) {
      const int p = tid + (j << 9);
      const int c = p >> 7, k = p & 127;
      const int row = (c0 + c < cnt) ? c0 + c : c0;
      sx[j] = x1g[(size_t)row * 1024 + (kc << 7) + k];
    }
  };
  auto wrlds = [&](int b) {
#pragma unroll
    for (int j = 0; j < 4; ++j) {
      const int p = tid + (j << 9);
      const int c = p >> 7, k = p & 127;
      xbuf[b][c * PSTR + k] = sx[j];
    }
  };

  f64x4 acc[8];
  const f64x4 z4 = {0.0, 0.0, 0.0, 0.0};
#pragma unroll
  for (int t = 0; t < 8; ++t) acc[t] = z4;

  ldregs(0);
  wrlds(0);
  __syncthreads();
  int buf = 0;
  for (int kc = 0; kc < 8; ++kc) {
    if (kc < 7) ldregs(kc + 1);          // async: loads in flight over MFMA
    const float* wrow = &Wfc[(size_t)((kc << 7) + quad) * 1024 + co_base + m];
    float wf[8];
#pragma unroll
    for (int t = 0; t < 8; ++t) wf[t] = wrow[t << 4];
    for (int k4 = 0; k4 < 32; ++k4) {
      float wn[8];
      if (k4 + 1 < 32) {
#pragma unroll
        for (int t = 0; t < 8; ++t)
          wn[t] = wrow[(size_t)((k4 + 1) << 2) * 1024 + (t << 4)];
      }
      const double a = xbuf[buf][m * PSTR + (k4 << 2) + quad];
#pragma unroll
      for (int t = 0; t < 8; ++t)
        acc[t] = __builtin_amdgcn_mfma_f64_16x16x4f64(a, (double)wf[t], acc[t], 0, 0, 0);
      if (k4 + 1 < 32) {
#pragma unroll
        for (int t = 0; t < 8; ++t) wf[t] = wn[t];
      }
    }
    if (kc < 7) wrlds(buf ^ 1);
    __syncthreads();
    buf ^= 1;
  }

  // heads: per lane, 4 cands (reg) x 8 co (t)
  double ps[4] = {0, 0, 0, 0}, py[4] = {0, 0, 0, 0}, px[4] = {0, 0, 0, 0};
#pragma unroll
  for (int t = 0; t < 8; ++t) {
    const int co = co_base + (t << 4) + m;
    const double bfv = (double)bfc[co];
    const double wsv = (double)Wsc[co];
    const double w0 = (double)Wrg[co * 2], w1 = (double)Wrg[co * 2 + 1];
#pragma unroll
    for (int rg = 0; rg < 4; ++rg) {
      double v = acc[t][rg] + bfv;
      v = v > 0.0 ? v : 0.0;
      ps[rg] = fma(v, wsv, ps[rg]);
      py[rg] = fma(v, w0, py[rg]);
      px[rg] = fma(v, w1, px[rg]);
    }
  }
  // butterfly over the 16 m-lanes (xor 1,2,4,8) — deterministic fixed order
#pragma unroll
  for (int off = 1; off <= 8; off <<= 1) {
#pragma unroll
    for (int rg = 0; rg < 4; ++rg) {
      ps[rg] += __shfl_xor(ps[rg], off, 64);
      py[rg] += __shfl_xor(py[rg], off, 64);
      px[rg] += __shfl_xor(px[rg], off, 64);
    }
  }
  if (m == 0) {
#pragma unroll
    for (int rg = 0; rg < 4; ++rg) {
      const int cand = (quad << 2) + rg;
      partw[0][wv][cand] = ps[rg];
      partw[1][wv][cand] = py[rg];
      partw[2][wv][cand] = px[rg];
    }
  }
  __syncthreads();
  if (tid < 48) {
    const int cand = tid & 15, h = tid >> 4;
    double s = 0.0;
#pragma unroll
    for (int w8 = 0; w8 < 8; ++w8) s += partw[h][w8][cand];
    if (c0 + cand < cnt) {
      if (h == 0) {
        const double lg = s + (double)bs[0];
        const double sg = 1.0 / (1.0 + exp(-lg));
        cand_sb[c0 + cand] = (unsigned long long)__double_as_longlong(sg);
      } else if (h == 1) cand_ry[c0 + cand] = s + (double)br[0];
      else               cand_rx[c0 + cand] = s + (double)br[1];
    }
  }
}

// ---------------------------------------------------------------------------
// proposal: f64 radix-select top-2000 (parallel suffix-scan bucket pick),
// DETERMINISTIC compaction, bitonic sort with (score desc, slot asc)
// tie-break, f64 NMS with LDS-resident neighbor lists, emit.
// Dynamic LDS layout (102400 B):
//   sk   ull [2048]      @ 0       16384
//   si   uint[2048]      @ 16384    8192
//   scan int [2048]      @ 24576    8192
//   nbrs u16 [2048*16]   @ 32768   65536
//   kept u8  [2048]      @ 98304    2048
//   nbrc u8  [2048]      @ 100352   2048
// ---------------------------------------------------------------------------
#define PROP_LDS 102400
__global__ __launch_bounds__(1024) void proposal_kernel(
    const unsigned int* __restrict__ cand_idx,
    const unsigned int* __restrict__ cand_cnt,
    const unsigned long long* __restrict__ cand_sb,
    const double* __restrict__ cand_ry, const double* __restrict__ cand_rx,
    unsigned int* __restrict__ cellrank,
    double* __restrict__ cyg, double* __restrict__ cxg,
    int* __restrict__ startb, float* __restrict__ out_ps,
    float* __restrict__ out_dec)
{
  extern __shared__ __align__(16) char dynsm[];
  unsigned long long* sk = (unsigned long long*)dynsm;
  unsigned int* si = (unsigned int*)(dynsm + 16384);
  int* scan = (int*)(dynsm + 24576);
  unsigned short* nbrs = (unsigned short*)(dynsm + 32768);
  unsigned char* kept = (unsigned char*)(dynsm + 98304);
  unsigned char* nbrc = (unsigned char*)(dynsm + 100352);

  __shared__ unsigned int hist[256];
  __shared__ unsigned long long sh_pref;
  __shared__ unsigned int sh_sub;
  __shared__ volatile unsigned int changed;
  __shared__ int sh_maxreg;

  const int tid = threadIdx.x;
  const int cnt = (int)*cand_cnt;

  for (int i = tid; i < 65536; i += 1024) cellrank[i] = 0xFFFFFFFFu;

  // ---- radix-select the 2000th-largest f64-score bit pattern
  unsigned long long prefix = 0ull;
  int need = KTOP;
  for (int byte = 7; byte >= 0; --byte) {
    if (tid < 256) hist[tid] = 0u;
    __syncthreads();
    const int sh = byte * 8;
    const unsigned long long mhi =
        (byte == 7) ? 0ull : (0xFFFFFFFFFFFFFFFFull << (sh + 8));
    for (int i = tid; i < cnt; i += 1024) {
      const unsigned long long k = cand_sb[i];
      if ((k & mhi) == prefix) atomicAdd(&hist[(unsigned int)((k >> sh) & 255u)], 1u);
    }
    __syncthreads();
    // in-place parallel suffix sum over buckets
    for (int off = 1; off < 256; off <<= 1) {
      unsigned int add = 0u;
      if (tid < 256 && tid + off < 256) add = hist[tid + off];
      __syncthreads();
      if (tid < 256) hist[tid] += add;
      __syncthreads();
    }
    if (tid < 256) {
      const unsigned int sv = hist[tid];
      const unsigned int above = (tid == 255) ? 0u : hist[tid + 1];
      if ((int)above < need && (int)sv >= need) {
        sh_pref = prefix | ((unsigned long long)(unsigned)tid << sh);
        sh_sub = above;
      }
    }
    __syncthreads();
    prefix = sh_pref;
    need -= (int)sh_sub;
    __syncthreads();
  }
  const unsigned long long T = prefix;

  // ---- deterministic compaction: thread t owns slots [4t, 4t+4)
  const int s0 = tid << 2;
  unsigned long long kv[4];
  int ca = 0, cb = 0;
#pragma unroll
  for (int q = 0; q < 4; ++q) {
    const int s = s0 + q;
    kv[q] = (s < cnt) ? cand_sb[s] : 0ull;
    if (s < cnt) { if (kv[q] > T) ++ca; else if (kv[q] == T) ++cb; }
  }
  scan[tid] = ca;
  __syncthreads();
  for (int off = 1; off < 1024; off <<= 1) {
    const int a = scan[tid];
    const int b = (tid >= off) ? scan[tid - off] : 0;
    __syncthreads();
    scan[tid] = a + b;
    __syncthreads();
  }
  int posA = scan[tid] - ca;         // exclusive
  const int atot = scan[1023];
  __syncthreads();
  scan[tid] = cb;
  __syncthreads();
  for (int off = 1; off < 1024; off <<= 1) {
    const int a = scan[tid];
    const int b = (tid >= off) ? scan[tid - off] : 0;
    __syncthreads();
    scan[tid] = a + b;
    __syncthreads();
  }
  int posB = atot + (scan[tid] - cb);
  __syncthreads();
#pragma unroll
  for (int q = 0; q < 4; ++q) {
    const int s = s0 + q;
    if (s < cnt) {
      if (kv[q] > T) {
        sk[posA] = kv[q]; si[posA] = (unsigned int)s; ++posA;
      } else if (kv[q] == T) {
        if (posB < KTOP) { sk[posB] = kv[q]; si[posB] = (unsigned int)s; }
        ++posB;
      }
    }
  }
  __syncthreads();
  for (int i = tid; i < 2048; i += 1024)
    if (i >= KTOP) { sk[i] = 0ull; si[i] = 0u; }
  if (tid == 0) sh_maxreg = 0;
  __syncthreads();

  // ---- bitonic sort 2048 descending by (score bits, then ascending slot)
  for (int k = 2; k <= 2048; k <<= 1) {
    for (int j = k >> 1; j > 0; j >>= 1) {
      const int i = (tid & (j - 1)) | ((tid & ~(j - 1)) << 1);
      const int ixj = i | j;
      const unsigned long long a = sk[i], b = sk[ixj];
      const unsigned int ia = si[i], ib = si[ixj];
      const bool up = ((i & k) == 0);
      const bool lt = (a < b) || (a == b && ia > ib);
      const bool gt = (a > b) || (a == b && ia < ib);
      if (up ? lt : gt) {
        sk[i] = b; sk[ixj] = a;
        si[i] = ib; si[ixj] = ia;
      }
      __syncthreads();
    }
  }

  // ---- decode top-2000 (f64)
  for (int r = tid; r < KTOP; r += 1024) {
    const unsigned int slot = si[r];
    const unsigned int idx = cand_idx[slot];
    const int row = (int)(idx >> 8), col = (int)(idx & 255u);
    const double ry = cand_ry[slot], rx = cand_rx[slot];
    cyg[r] = ((double)row + 0.5) + ry;
    cxg[r] = ((double)col + 0.5) + rx;
    kept[r] = 1; nbrc[r] = 0;
    cellrank[idx] = (unsigned int)r;
    atomicMax(&sh_maxreg, __float_as_int((float)fabs(ry)));
    atomicMax(&sh_maxreg, __float_as_int((float)fabs(rx)));
  }
  __syncthreads();
  const float maxreg = __int_as_float(sh_maxreg);
  int rad = (int)(1.0f + 2.0f * maxreg) + 1;
  if (rad > 8) rad = 8;
  if (rad < 1) rad = 1;

  // ---- earlier-close neighbor lists into LDS (f64 distances)
  for (int r = tid; r < KTOP; r += 1024) {
    const unsigned int idx = cand_idx[si[r]];
    const int row = (int)(idx >> 8), col = (int)(idx & 255u);
    int n = 0;
    const double pyr = cyg[r], pxr = cxg[r];
    for (int dy = -rad; dy <= rad; ++dy) {
      const int yy = row + dy; if (yy < 0 || yy >= 256) continue;
      for (int dx = -rad; dx <= rad; ++dx) {
        if (dy == 0 && dx == 0) continue;
        const int xx = col + dx; if (xx < 0 || xx >= 256) continue;
        const unsigned int q = cellrank[yy * 256 + xx];
        if (q < (unsigned int)r) {
          const double t1 = __dsub_rn(pyr, cyg[q]);
          const double t2 = __dsub_rn(pxr, cxg[q]);
          const double d2 = __dadd_rn(__dmul_rn(t1, t1), __dmul_rn(t2, t2));
          if (d2 < 1.0) { if (n < 16) nbrs[(r << 4) + n] = (unsigned short)q; ++n; }
        }
      }
    }
    nbrc[r] = (unsigned char)(n < 16 ? n : 16);
  }
  __syncthreads();

  // ---- fixpoint == sequential NMS (unique fixpoint on rank-DAG), LDS-only
  for (int it = 0; it < 4096; ++it) {
    __syncthreads();
    if (tid == 0) changed = 0;
    __syncthreads();
    for (int r = tid; r < KTOP; r += 1024) {
      const int nc = nbrc[r];
      if (nc) {
        int kvv = 1;
        for (int t = 0; t < nc; ++t)
          if (kept[nbrs[(r << 4) + t]]) { kvv = 0; break; }
        if (kvv != (int)kept[r]) { kept[r] = (unsigned char)kvv; changed = 1; }
      }
    }
    __syncthreads();
    if (changed == 0) break;
  }

  // ---- inclusive prefix scan of kept
  scan[tid]        = (tid < KTOP) ? (int)kept[tid] : 0;
  scan[tid + 1024] = (tid + 1024 < KTOP) ? (int)kept[tid + 1024] : 0;
  __syncthreads();
  for (int off = 1; off < 2048; off <<= 1) {
    const int a0 = scan[tid];
    const int b0 = (tid >= off) ? scan[tid - off] : 0;
    const int a1 = scan[tid + 1024];
    const int b1 = (tid + 1024 >= off) ? scan[tid + 1024 - off] : 0;
    __syncthreads();
    scan[tid] = a0 + b0;
    scan[tid + 1024] = a1 + b1;
    __syncthreads();
  }
  const int total = scan[KTOP - 1];

  // ---- emit
  for (int r = tid; r < KTOP; r += 1024) {
    int slot = -1;
    if (kept[r]) { const int p = scan[r] - 1; if (p < MAXOUT) slot = p; }
    else { const int p = total + (r - scan[r]); if (p < MAXOUT) slot = p; }
    if (slot >= 0) {
      const double sg = __longlong_as_double((long long)sk[r]);
      out_ps[slot] = kept[r] ? (float)sg : -1.0f;
      const double py = cyg[r], px = cxg[r];
      out_dec[slot * 2]     = (float)(py * 4.0);
      out_dec[slot * 2 + 1] = (float)(px * 4.0);
      int sy = (int)rint(py * 2.0 - 24.0);
      int sx = (int)rint(px * 2.0 - 24.0);
      sy = sy < 0 ? 0 : (sy > 464 ? 464 : sy);
      sx = sx < 0 ? 0 : (sx > 464 ? 464 : sx);
      startb[slot * 2] = sy; startb[slot * 2 + 1] = sx;
    }
  }
}

// ---------------------------------------------------------------------------
// conv_i via bf16 MFMA: 3x3 32->64 + relu on 48x48 crops -> h (bf16).
// ---------------------------------------------------------------------------
#define ISTR 40   // input pixel stride in bf16 elems (80 B)
__global__ __launch_bounds__(256) void conv_i_mfma(
    const float* __restrict__ seg, const unsigned short* __restrict__ WiB,
    const float* __restrict__ bi, const int* __restrict__ startb,
    unsigned short* __restrict__ h, int inst0)
{
  __shared__ __align__(16) unsigned short ins[500 * ISTR];   // 40 KB (reused)
  const int li = blockIdx.y;
  const int inst = inst0 + li;
  const int tile = blockIdx.x;              // 0..5
  const int r0 = tile << 3;
  const int tid = threadIdx.x;
  const int sy = startb[inst * 2], sx = startb[inst * 2 + 1];

  for (int p = tid; p < 500; p += 256) {
    const int rr = p / 50, cc2 = p - rr * 50;
    const int ir = r0 - 1 + rr, ic = cc2 - 1;
    unsigned short* dst = &ins[p * ISTR];
    if (ir >= 0 && ir < 48 && ic >= 0 && ic < 48) {
      const float* src = &seg[((size_t)(sy + ir) * 512 + (sx + ic)) * 32];
#pragma unroll
      for (int q = 0; q < 8; ++q) {
        const float4 v = *(const float4*)&src[q << 2];
        const unsigned int lo = (unsigned int)f2bf(v.x) | ((unsigned int)f2bf(v.y) << 16);
        const unsigned int hi = (unsigned int)f2bf(v.z) | ((unsigned int)f2bf(v.w) << 16);
        *(uint2*)&dst[q << 2] = make_uint2(lo, hi);
      }
    } else {
#pragma unroll
      for (int q = 0; q < 4; ++q) *(uint4*)&dst[q << 3] = make_uint4(0, 0, 0, 0);
    }
  }
  __syncthreads();

  const int wv = tid >> 6, lane = tid & 63;
  const int l15 = lane & 15, quad = lane >> 4;
  const int wmb = wv * 96;

  int pbase[6];
#pragma unroll
  for (int i = 0; i < 6; ++i) {
    const int m = wmb + (i << 4) + l15;
    pbase[i] = (m / 48 + 1) * 50 + (m % 48) + 1;
  }

  f32x4 acc[6][4];
  const f32x4 z4 = {0.f, 0.f, 0.f, 0.f};
#pragma unroll
  for (int i = 0; i < 6; ++i)
#pragma unroll
    for (int j = 0; j < 4; ++j) acc[i][j] = z4;

  for (int tap = 0; tap < 9; ++tap) {
    const int off = (tap / 3 - 1) * 50 + (tap % 3 - 1);
    short8 b[4];
#pragma unroll
    for (int j = 0; j < 4; ++j)
      b[j] = *(const short8*)&WiB[((tap << 6) + (j << 4) + l15) * 32 + (quad << 3)];
#pragma unroll
    for (int i = 0; i < 6; ++i) {
      const short8 a = *(const short8*)&ins[(pbase[i] + off) * ISTR + (quad << 3)];
#pragma unroll
      for (int j = 0; j < 4; ++j)
        acc[i][j] = __builtin_amdgcn_mfma_f32_16x16x32_bf16(a, b[j], acc[i][j], 0, 0, 0);
    }
  }

  float bv[4];
#pragma unroll
  for (int j = 0; j < 4; ++j) bv[j] = bi[(j << 4) + l15];

  for (int half = 0; half < 2; ++half) {
    __syncthreads();
    if ((wv >> 1) == half) {
#pragma unroll
      for (int i = 0; i < 6; ++i)
#pragma unroll
        for (int j = 0; j < 4; ++j)
#pragma unroll
          for (int rg = 0; rg < 4; ++rg) {
            const int m = wmb + (i << 4) + (quad << 2) + rg;
            const int pp = m - half * 192;
            const float v = fmaxf(acc[i][j][rg] + bv[j], 0.f);
            ins[pp * 72 + (j << 4) + l15] = f2bf(v);
          }
    }
    __syncthreads();
    for (int t = tid; t < 192 * 8; t += 256) {
      const int pp = t >> 3, c8 = t & 7;
      const uint4 v = *(const uint4*)&ins[pp * 72 + (c8 << 3)];
      *(uint4*)&h[((size_t)li * 2304 + (tile * 384 + half * 192 + pp)) * 64 + (c8 << 3)] = v;
    }
  }
}

// ---------------------------------------------------------------------------
// conv_o: 3x3, 64->1 + sigmoid on bf16 h; emits instance_coords.
// ---------------------------------------------------------------------------
__global__ __launch_bounds__(256) void conv_o_kernel(
    const unsigned short* __restrict__ h, const float* __restrict__ Wo,
    const float* __restrict__ bo, const int* __restrict__ startb,
    float* __restrict__ out_io, float* __restrict__ out_ic, int inst0)
{
  __shared__ __align__(16) unsigned short hs[324 * 72];   // 46.7 KB
  __shared__ float wos[576];
  const int li = blockIdx.y;
  const int inst = inst0 + li;
  const int tile = blockIdx.x;
  const int ty0 = (tile / 3) << 4;
  const int tx0 = (tile % 3) << 4;
  const int tid = threadIdx.x;

  for (int i = tid; i < 576; i += 256) wos[i] = Wo[i];
  for (int p = tid; p < 324; p += 256) {
    const int iy = p / 18, ix = p - iy * 18;
    const int gy = ty0 - 1 + iy, gx = tx0 - 1 + ix;
    unsigned short* dst = &hs[p * 72];
    if (gy >= 0 && gy < 48 && gx >= 0 && gx < 48) {
      const unsigned short* src = &h[((size_t)li * 2304 + gy * 48 + gx) * 64];
#pragma unroll
      for (int q = 0; q < 8; ++q) *(uint4*)&dst[q << 3] = *(const uint4*)&src[q << 3];
    } else {
#pragma unroll
      for (int q = 0; q < 8; ++q) *(uint4*)&dst[q << 3] = make_uint4(0, 0, 0, 0);
    }
  }
  __syncthreads();

  const int ly = tid >> 4, lx = tid & 15;
  float a = 0.f;
#pragma unroll
  for (int ky = 0; ky < 3; ++ky)
#pragma unroll
    for (int kx = 0; kx < 3; ++kx) {
      const unsigned short* hp = &hs[((ly + ky) * 18 + lx + kx) * 72];
      const float* wp = &wos[(ky * 3 + kx) << 6];
#pragma unroll
      for (int c8 = 0; c8 < 8; ++c8) {
        const uint4 hv = *(const uint4*)&hp[c8 << 3];
        const unsigned int uu[4] = {hv.x, hv.y, hv.z, hv.w};
#pragma unroll
        for (int e = 0; e < 4; ++e) {
          const float f0 = __uint_as_float(uu[e] << 16);
          const float f1 = __uint_as_float(uu[e] & 0xFFFF0000u);
          a = fmaf(f0, wp[(c8 << 3) + (e << 1)], a);
          a = fmaf(f1, wp[(c8 << 3) + (e << 1) + 1], a);
        }
      }
    }
  a += bo[0];
  const float o = 1.f / (1.f + expf(-a));
  const int gy = ty0 + ly, gx = tx0 + lx;
  const size_t p = ((size_t)inst * 48 + gy) * 48 + gx;
  out_io[p] = o;
  const int sy = startb[inst * 2], sx = startb[inst * 2 + 1];
  out_ic[p * 2]     = (float)(sy + gy);
  out_ic[p * 2 + 1] = (float)(sx + gx);
}

// ---------------------------------------------------------------------------
extern "C" void kernel_launch(void* const* d_in, const int* in_sizes, int n_in,
                              void* d_out, int out_size, void* d_ws, size_t ws_size,
                              hipStream_t stream)
{
  const float* df  = (const float*)d_in[0];
  const float* seg = (const float*)d_in[1];
  const float* Wc  = (const float*)d_in[2];
  const float* bc  = (const float*)d_in[3];
  const float* Wfc = (const float*)d_in[4];
  const float* bfc = (const float*)d_in[5];
  const float* Wsc = (const float*)d_in[6];
  const float* bs  = (const float*)d_in[7];
  const float* Wrg = (const float*)d_in[8];
  const float* br  = (const float*)d_in[9];
  const float* Wi  = (const float*)d_in[10];
  const float* bi  = (const float*)d_in[11];
  const float* Wo  = (const float*)d_in[12];
  const float* bo  = (const float*)d_in[13];

  const size_t SZ_WCT = 2359296ull, SZ_WFT = 2097152ull, SZ_WIB = 36864ull,
               SZ_DFB = 17040384ull,                      // 258*258*128 bf16
               SZ_PART = 2097152ull, SZ_SC = 262144ull, SZ_CR = 262144ull,
               SZ_STB = 4096ull, SZ_CI = CANDCAP * 4ull,
               SZ_SB = CANDCAP * 8ull, SZ_RY = CANDCAP * 8ull,
               SZ_RX = CANDCAP * 8ull, SZ_CY = 16384ull, SZ_CX = 16384ull,
               SZ_X1G = (size_t)CANDCAP * 1024ull * 8ull,   // 33.5 MB, own slot
               SZ_CNT = 256ull;
  const size_t FIXED = SZ_WCT + SZ_WFT + SZ_WIB + SZ_DFB + SZ_PART + SZ_SC +
                       SZ_CR + SZ_STB + SZ_CI + SZ_SB + SZ_RY + SZ_RX +
                       SZ_CY + SZ_CX + SZ_X1G + SZ_CNT;
  char* w = (char*)d_ws;
  size_t region = (ws_size > FIXED) ? ((ws_size - FIXED) & ~(size_t)255) : 0;
  char* fb = w + region;
  unsigned short* WcT = (unsigned short*)fb;   fb += SZ_WCT;
  unsigned short* WfcT = (unsigned short*)fb;  fb += SZ_WFT;
  unsigned short* WiB = (unsigned short*)fb;   fb += SZ_WIB;
  unsigned short* dfb = (unsigned short*)fb;   fb += SZ_DFB;
  float* part = (float*)fb;                    fb += SZ_PART;
  float* scores = (float*)fb;                  fb += SZ_SC;
  unsigned int* cellrank = (unsigned int*)fb;  fb += SZ_CR;
  int* startb = (int*)fb;                      fb += SZ_STB;
  unsigned int* cand_idx = (unsigned int*)fb;  fb += SZ_CI;
  unsigned long long* cand_sb = (unsigned long long*)fb; fb += SZ_SB;
  double* cand_ry = (double*)fb;               fb += SZ_RY;
  double* cand_rx = (double*)fb;               fb += SZ_RX;
  double* cyg = (double*)fb;                   fb += SZ_CY;
  double* cxg = (double*)fb;                   fb += SZ_CX;
  double* x1g = (double*)fb;                   fb += SZ_X1G;
  unsigned int* cand_cnt = (unsigned int*)fb;
  unsigned short* x1b = (unsigned short*)w;    // big region: bf16 x1 chunk
  unsigned short* hb = (unsigned short*)w;     // big region: bf16 inst crops

  size_t tiles_fit = region / 131072ull;
  int pt_chunk = 4;                            // 256-row tiles need mult of 4
  while ((size_t)(pt_chunk * 2) <= tiles_fit && pt_chunk < 1024) pt_chunk <<= 1;
  size_t inst_fit = region / 294912ull;        // 48*48*64*2B per instance
  const int opts[12] = {500, 250, 125, 100, 50, 25, 20, 10, 5, 4, 2, 1};
  int inst_chunk = 1;
  for (int o = 0; o < 12; ++o)
    if ((size_t)opts[o] <= inst_fit) { inst_chunk = opts[o]; break; }

  float* out = (float*)d_out;
  float* out_ps  = out;
  float* out_dec = out + 500;
  float* out_io  = out + 1500;
  float* out_ic  = out + 1153500;

  transpose_bf16_kernel<<<dim3(36, 32), 256, 0, stream>>>(Wc, WcT, 1152, 1024);
  transpose_bf16_kernel<<<dim3(32, 32), 256, 0, stream>>>(Wfc, WfcT, 1024, 1024);
  prep_wib_kernel<<<72, 256, 0, stream>>>(Wi, WiB);
  pad_df_bf16<<<4161, 256, 0, stream>>>(df, dfb);

  for (int c = 0; c < 1024 / pt_chunk; ++c) {
    conv1_mfma<<<dim3(4, pt_chunk / 4), 512, 0, stream>>>(dfb, WcT, bc, x1b,
                                                          c * pt_chunk);
    fc_mfma<<<dim3(4, pt_chunk / 4), 512, 0, stream>>>(x1b, WfcT, bfc, Wsc,
                                                       part, c * pt_chunk);
  }
  head_finalize_kernel<<<256, 256, 0, stream>>>(part, bs, scores);
  select_kernel<<<1, 1024, 0, stream>>>(scores, cand_idx, cand_cnt);
  rescore_conv<<<(CANDCAP / RCC) * 2, 512, 0, stream>>>(df, Wc, bc, cand_idx,
                                                        cand_cnt, x1g);
  rescore_fc<<<CANDCAP / RC2, 512, 0, stream>>>(x1g, Wfc, bfc, Wsc, bs, Wrg,
                                                br, cand_cnt, cand_sb,
                                                cand_ry, cand_rx);
  proposal_kernel<<<1, 1024, PROP_LDS, stream>>>(cand_idx, cand_cnt, cand_sb,
                                                 cand_ry, cand_rx, cellrank,
                                                 cyg, cxg, startb, out_ps,
                                                 out_dec);
  for (int c = 0; c < 500 / inst_chunk; ++c) {
    conv_i_mfma<<<dim3(6, inst_chunk), 256, 0, stream>>>(seg, WiB, bi, startb,
                                                         hb, c * inst_chunk);
    conv_o_kernel<<<dim3(9, inst_chunk), 256, 0, stream>>>(hb, Wo, bo, startb,
                                                           out_io, out_ic,
                                                           c * inst_chunk);
  }
}